// Round 1
// baseline (638.191 us; speedup 1.0000x reference)
//
#include <hip/hip_runtime.h>
#include <math.h>

#define Bsz 4
#define Nseq 2048
#define Cdim 512
#define Hn 8
#define Dh 64
#define TK 256
#define BH (Bsz*Hn)          // 32
#define MROWS (Bsz*Nseq)     // 8192
#define QKVC 1536

// ---------------------------------------------------------------
// fp32 tiled GEMM: C[M x Nn] = A[M x K] * B[K x Nn] (+ bias)
// 128x128 block tile, BK=16, 256 threads, 8x8 per thread.
// ---------------------------------------------------------------
__global__ __launch_bounds__(256) void gemm128(const float* __restrict__ A,
                                               const float* __restrict__ Bm,
                                               const float* __restrict__ bias,
                                               float* __restrict__ Cout,
                                               int K, int Nn) {
    __shared__ float As[16][132];
    __shared__ float Bs[16][132];
    int tid = threadIdx.x;
    int m0 = blockIdx.y * 128, n0 = blockIdx.x * 128;
    int tx = tid & 15, ty = tid >> 4;   // 16 x 16 thread grid
    float acc[8][8];
    #pragma unroll
    for (int r = 0; r < 8; ++r)
        #pragma unroll
        for (int c = 0; c < 8; ++c) acc[r][c] = 0.0f;

    int ka = tid & 15, ia = tid >> 4;   // A staging: k, row
    int jb = tid & 127, kb = tid >> 7;  // B staging: col, k

    for (int k0 = 0; k0 < K; k0 += 16) {
        #pragma unroll
        for (int p = 0; p < 8; ++p)
            As[ka][ia + p * 16] = A[(size_t)(m0 + ia + p * 16) * K + k0 + ka];
        #pragma unroll
        for (int p = 0; p < 8; ++p)
            Bs[kb + p * 2][jb] = Bm[(size_t)(k0 + kb + p * 2) * Nn + n0 + jb];
        __syncthreads();
        #pragma unroll
        for (int kk = 0; kk < 16; ++kk) {
            float a[8], b[8];
            #pragma unroll
            for (int r = 0; r < 8; ++r) a[r] = As[kk][ty * 8 + r];
            // cols: tx*4 .. tx*4+3  and  64+tx*4 .. 64+tx*4+3 (2-way LDS, free)
            #pragma unroll
            for (int c = 0; c < 4; ++c) b[c] = Bs[kk][tx * 4 + c];
            #pragma unroll
            for (int c = 0; c < 4; ++c) b[4 + c] = Bs[kk][64 + tx * 4 + c];
            #pragma unroll
            for (int r = 0; r < 8; ++r)
                #pragma unroll
                for (int c = 0; c < 8; ++c) acc[r][c] += a[r] * b[c];
        }
        __syncthreads();
    }
    float bi[8];
    #pragma unroll
    for (int c = 0; c < 4; ++c) {
        bi[c]     = bias ? bias[n0 + tx * 4 + c]      : 0.0f;
        bi[4 + c] = bias ? bias[n0 + 64 + tx * 4 + c] : 0.0f;
    }
    #pragma unroll
    for (int r = 0; r < 8; ++r) {
        size_t rowoff = (size_t)(m0 + ty * 8 + r) * Nn;
        #pragma unroll
        for (int c = 0; c < 4; ++c) {
            Cout[rowoff + n0 + tx * 4 + c]      = acc[r][c]     + bi[c];
            Cout[rowoff + n0 + 64 + tx * 4 + c] = acc[r][4 + c] + bi[4 + c];
        }
    }
}

// ---------------------------------------------------------------
// per-(b,h): q_mean, k_mean, sum_v
// ---------------------------------------------------------------
__global__ __launch_bounds__(256) void stats_kernel(const float* __restrict__ qkv,
                                                    float* qmean, float* kmean, float* sv) {
    int bh = blockIdx.x; int b = bh >> 3; int h = bh & 7;
    int tid = threadIdx.x; int d = tid & 63; int g = tid >> 6;
    const float* base = qkv + (size_t)b * Nseq * QKVC + h * Dh + d;
    float sq = 0.f, sk = 0.f, svv = 0.f;
    for (int n = g; n < Nseq; n += 4) {
        const float* p = base + (size_t)n * QKVC;
        sq += p[0]; sk += p[512]; svv += p[1024];
    }
    __shared__ float red[3][4][64];
    red[0][g][d] = sq; red[1][g][d] = sk; red[2][g][d] = svv;
    __syncthreads();
    if (tid < 64) {
        float a  = red[0][0][d] + red[0][1][d] + red[0][2][d] + red[0][3][d];
        float k2 = red[1][0][d] + red[1][1][d] + red[1][2][d] + red[1][3][d];
        float v2 = red[2][0][d] + red[2][1][d] + red[2][2][d] + red[2][3][d];
        qmean[bh * 64 + d] = a  * (1.0f / Nseq);
        kmean[bh * 64 + d] = k2 * (1.0f / Nseq);
        sv[bh * 64 + d]    = v2;
    }
}

// ---------------------------------------------------------------
// row score_i = scale*q_i.k_mean ; col score_j = scale*q_mean.k_j
// ---------------------------------------------------------------
__global__ __launch_bounds__(256) void score_kernel(const float* __restrict__ qkv,
                                                    const float* __restrict__ qmean,
                                                    const float* __restrict__ kmean,
                                                    float* rsc, float* csc) {
    int bh = blockIdx.x; int b = bh >> 3, h = bh & 7;
    int i = blockIdx.y * 256 + threadIdx.x;
    __shared__ float qm[64], km[64];
    if (threadIdx.x < 64) {
        qm[threadIdx.x] = qmean[bh * 64 + threadIdx.x];
        km[threadIdx.x] = kmean[bh * 64 + threadIdx.x];
    }
    __syncthreads();
    const float* qp = qkv + (size_t)b * Nseq * QKVC + (size_t)i * QKVC + h * Dh;
    float r = 0.f, c = 0.f;
    #pragma unroll 8
    for (int d = 0; d < 64; ++d) { r += qp[d] * km[d]; c += qp[512 + d] * qm[d]; }
    rsc[(size_t)bh * Nseq + i] = r * 0.125f;
    csc[(size_t)bh * Nseq + i] = c * 0.125f;
}

// ---------------------------------------------------------------
// top-256 of 2048 by rank counting on packed (value,index) keys.
// Exact jax.lax.top_k tie semantics (value desc, index asc).
// Ranks form a permutation -> outp[rank]=i needs no scan.
// ---------------------------------------------------------------
__global__ __launch_bounds__(256) void topk_kernel(const float* __restrict__ rsc,
                                                   const float* __restrict__ csc,
                                                   int* ridx, int* cidx) {
    int selid = blockIdx.y;
    int bh = selid >> 1, which = selid & 1;
    const float* sin = which ? (csc + (size_t)bh * Nseq) : (rsc + (size_t)bh * Nseq);
    int* outp = which ? (cidx + bh * TK) : (ridx + bh * TK);
    __shared__ unsigned long long keys[Nseq];
    int tid = threadIdx.x;
    for (int i = tid; i < Nseq; i += 256) {
        unsigned u = __float_as_uint(sin[i]);
        u = (u & 0x80000000u) ? ~u : (u | 0x80000000u);
        keys[i] = ((unsigned long long)u << 32) | (unsigned)(Nseq - 1 - i);
    }
    __syncthreads();
    int i = blockIdx.x * 256 + tid;
    unsigned long long ki = keys[i];
    int rank = 0;
    #pragma unroll 8
    for (int j = 0; j < Nseq; ++j) rank += (keys[j] > ki) ? 1 : 0;
    if (rank < TK) outp[rank] = i;
}

// ---------------------------------------------------------------
// sum of v over the 256 selected columns
// ---------------------------------------------------------------
__global__ __launch_bounds__(256) void svsel_kernel(const float* __restrict__ qkv,
                                                    const int* __restrict__ cidx,
                                                    float* svsel) {
    int bh = blockIdx.x; int b = bh >> 3, h = bh & 7;
    int tid = threadIdx.x; int d = tid & 63, g = tid >> 6;
    float sum = 0.f;
    for (int j = g; j < TK; j += 4) {
        int col = cidx[bh * TK + j];
        sum += qkv[(size_t)b * Nseq * QKVC + (size_t)col * QKVC + 1024 + h * Dh + d];
    }
    __shared__ float red[4][64];
    red[g][d] = sum;
    __syncthreads();
    if (tid < 64) svsel[bh * 64 + d] = red[0][d] + red[1][d] + red[2][d] + red[3][d];
}

// ---------------------------------------------------------------
// E kernel: for each selected row i, s_ij over 256 selected cols,
// e_ij = exp(s-m), m = max(0, max s). Stores E, exp(-m), 1/Z.
// K_sel^T staged in 64KB LDS (conflict-free both phases).
// ---------------------------------------------------------------
__global__ __launch_bounds__(256) void attn_e_kernel(const float* __restrict__ qkv,
                                                     const int* __restrict__ ridx,
                                                     const int* __restrict__ cidx,
                                                     float* __restrict__ Ebuf,
                                                     float* um, float* invZ) {
    int bh = blockIdx.x; int b = bh >> 3, h = bh & 7;
    int rblk = blockIdx.y;
    __shared__ float Kt[64 * 256];     // Kt[d*256 + j] = k_sel[j][d]; 64KB
    int tid = threadIdx.x;
    {
        int j = tid;
        int col = cidx[bh * TK + j];
        const float* kp = qkv + (size_t)b * Nseq * QKVC + (size_t)col * QKVC + 512 + h * Dh;
        #pragma unroll 8
        for (int d = 0; d < 64; ++d) Kt[d * 256 + j] = kp[d];   // banks=j%32: free
    }
    __syncthreads();
    int wave = tid >> 6, lane = tid & 63;
    for (int rr = 0; rr < 16; ++rr) {
        int i = rblk * 64 + wave * 16 + rr;
        int row = ridx[bh * TK + i];
        float qv = qkv[(size_t)b * Nseq * QKVC + (size_t)row * QKVC + h * Dh + lane];
        float s0 = 0.f, s1 = 0.f, s2 = 0.f, s3 = 0.f;
        #pragma unroll 8
        for (int d = 0; d < 64; ++d) {
            float qd = __shfl(qv, d, 64);
            const float* kr = &Kt[d * 256 + lane];
            s0 += qd * kr[0];
            s1 += qd * kr[64];
            s2 += qd * kr[128];
            s3 += qd * kr[192];
        }
        s0 *= 0.125f; s1 *= 0.125f; s2 *= 0.125f; s3 *= 0.125f;
        float mx = fmaxf(fmaxf(s0, s1), fmaxf(s2, s3));
        #pragma unroll
        for (int off = 32; off; off >>= 1) mx = fmaxf(mx, __shfl_xor(mx, off, 64));
        mx = fmaxf(mx, 0.0f);
        float e0 = __expf(s0 - mx), e1 = __expf(s1 - mx);
        float e2 = __expf(s2 - mx), e3 = __expf(s3 - mx);
        float zs = e0 + e1 + e2 + e3;
        #pragma unroll
        for (int off = 32; off; off >>= 1) zs += __shfl_xor(zs, off, 64);
        float em = __expf(-mx);
        float Z = (float)(Nseq - TK) * em + zs;
        float* ep = Ebuf + ((size_t)bh * TK + i) * TK;
        ep[lane] = e0; ep[lane + 64] = e1; ep[lane + 128] = e2; ep[lane + 192] = e3;
        if (lane == 0) { um[bh * TK + i] = em; invZ[bh * TK + i] = 1.0f / Z; }
    }
}

// ---------------------------------------------------------------
// fill all context rows with the uniform-softmax value mean(v)
// ---------------------------------------------------------------
__global__ __launch_bounds__(256) void fill_uniform(const float* __restrict__ sv,
                                                    float* __restrict__ hctx) {
    int idx = blockIdx.x * 256 + threadIdx.x;      // < B*N*C = 2^22
    int c = idx & 511;
    int b = idx >> 20;                              // N*C = 2^20
    int head = c >> 6, d = c & 63;
    hctx[idx] = sv[((b << 3) + head) * 64 + d] * (1.0f / Nseq);
}

// ---------------------------------------------------------------
// AV kernel: out_i = (e^{-m}(Sv - Sv_sel) + sum_j e_ij v_j) / Z
// V_sel staged in 64KB LDS (coalesced stage, conflict-free reads).
// ---------------------------------------------------------------
__global__ __launch_bounds__(256) void attn_av_kernel(const float* __restrict__ qkv,
                                                      const int* __restrict__ ridx,
                                                      const int* __restrict__ cidx,
                                                      const float* __restrict__ Ebuf,
                                                      const float* __restrict__ um,
                                                      const float* __restrict__ invZ,
                                                      const float* __restrict__ sv,
                                                      const float* __restrict__ svsel,
                                                      float* __restrict__ hctx) {
    int bh = blockIdx.x; int b = bh >> 3, h = bh & 7;
    int rblk = blockIdx.y;
    __shared__ float Vs[TK * 64];      // Vs[j*64 + d]; 64KB
    int tid = threadIdx.x;
    size_t vbase = (size_t)b * Nseq * QKVC + 1024 + h * Dh;
    for (int idx = tid; idx < TK * 64; idx += 256) {
        int j = idx >> 6, d = idx & 63;
        Vs[idx] = qkv[vbase + (size_t)cidx[bh * TK + j] * QKVC + d];
    }
    __syncthreads();
    int wave = tid >> 6, lane = tid & 63;
    float sadj = sv[bh * 64 + lane] - svsel[bh * 64 + lane];
    for (int rr = 0; rr < 16; ++rr) {
        int i = rblk * 64 + wave * 16 + rr;
        const float* ep = Ebuf + ((size_t)bh * TK + i) * TK;
        float e0 = ep[lane], e1 = ep[lane + 64], e2 = ep[lane + 128], e3 = ep[lane + 192];
        float acc = 0.f;
        #pragma unroll 4
        for (int j = 0; j < 64; ++j) {
            float w0 = __shfl(e0, j, 64), w1 = __shfl(e1, j, 64);
            float w2 = __shfl(e2, j, 64), w3 = __shfl(e3, j, 64);
            acc += w0 * Vs[j * 64 + lane];
            acc += w1 * Vs[(j + 64) * 64 + lane];
            acc += w2 * Vs[(j + 128) * 64 + lane];
            acc += w3 * Vs[(j + 192) * 64 + lane];
        }
        float outv = (um[bh * TK + i] * sadj + acc) * invZ[bh * TK + i];
        int row = ridx[bh * TK + i];
        hctx[(size_t)b * Nseq * Cdim + (size_t)row * Cdim + h * Dh + lane] = outv;
    }
}

extern "C" void kernel_launch(void* const* d_in, const int* in_sizes, int n_in,
                              void* d_out, int out_size, void* d_ws, size_t ws_size,
                              hipStream_t stream) {
    const float* x     = (const float*)d_in[0];
    const float* w_qkv = (const float*)d_in[1];
    const float* w_out = (const float*)d_in[2];
    const float* b_out = (const float*)d_in[3];
    float* out = (float*)d_out;

    float* ws    = (float*)d_ws;
    float* qkv   = ws;                                  // B*N*3C = 12,582,912
    float* qmean = qkv + (size_t)Bsz * Nseq * QKVC;     // BH*D
    float* kmean = qmean + BH * Dh;
    float* sv    = kmean + BH * Dh;
    float* svsel = sv + BH * Dh;
    float* rsc   = svsel + BH * Dh;                     // BH*N
    float* csc   = rsc + (size_t)BH * Nseq;
    int*   ridx  = (int*)(csc + (size_t)BH * Nseq);     // BH*TK
    int*   cidx  = ridx + BH * TK;
    float* um    = (float*)(cidx + BH * TK);
    float* invZ  = um + BH * TK;
    float* Ebuf  = invZ + BH * TK;                      // BH*TK*TK = 2,097,152
    float* hctx  = Ebuf + (size_t)BH * TK * TK;         // B*N*C = 4,194,304

    // 1. qkv = x @ w_qkv  (fp32; must stay fp32 for top-k exactness)
    gemm128<<<dim3(QKVC / 128, MROWS / 128), 256, 0, stream>>>(x, w_qkv, nullptr, qkv, Cdim, QKVC);
    // 2. per-(b,h) means / sums
    stats_kernel<<<BH, 256, 0, stream>>>(qkv, qmean, kmean, sv);
    // 3. rank-1 row/col scores
    score_kernel<<<dim3(BH, Nseq / 256), 256, 0, stream>>>(qkv, qmean, kmean, rsc, csc);
    // 4. top-256 selections (rows and cols)
    topk_kernel<<<dim3(Nseq / 256, BH * 2), 256, 0, stream>>>(rsc, csc, ridx, cidx);
    // 5. sum of v over selected cols
    svsel_kernel<<<BH, 256, 0, stream>>>(qkv, cidx, svsel);
    // 6. scores+exp for selected 256x256 block
    attn_e_kernel<<<dim3(BH, 4), 256, 0, stream>>>(qkv, ridx, cidx, Ebuf, um, invZ);
    // 7. uniform rows (softmax of all-zero row)
    fill_uniform<<<(Bsz * Nseq * Cdim) / 256, 256, 0, stream>>>(sv, hctx);
    // 8. selected rows: weighted V
    attn_av_kernel<<<dim3(BH, 4), 256, 0, stream>>>(qkv, ridx, cidx, Ebuf, um, invZ, sv, svsel, hctx);
    // 9. out = hctx @ w_out + b_out
    gemm128<<<dim3(Cdim / 128, MROWS / 128), 256, 0, stream>>>(hctx, w_out, b_out, out, Cdim, Cdim);
}

// Round 2
// 477.665 us; speedup vs baseline: 1.3361x; 1.3361x over previous
//
#include <hip/hip_runtime.h>
#include <math.h>

#define Bsz 4
#define Nseq 2048
#define Cdim 512
#define Hn 8
#define Dh 64
#define TK 256
#define BH (Bsz*Hn)          // 32
#define MROWS (Bsz*Nseq)     // 8192
#define QKVC 1536

typedef __attribute__((ext_vector_type(8))) short bf16x8;
typedef __attribute__((ext_vector_type(4))) float f32x4;

__device__ __forceinline__ unsigned short f2bf(float x) {
    unsigned u = __float_as_uint(x);
    unsigned r = (u + 0x7fffu + ((u >> 16) & 1u)) >> 16;   // round-to-nearest-even
    return (unsigned short)r;
}
__device__ __forceinline__ float bf2f(unsigned short h) {
    return __uint_as_float((unsigned)h << 16);
}

__device__ __forceinline__ void gll16(const void* g, void* l) {
    __builtin_amdgcn_global_load_lds((const __attribute__((address_space(1))) unsigned int*)g,
                                     (__attribute__((address_space(3))) unsigned int*)l,
                                     16, 0, 0);
}

// ---------------------------------------------------------------
// elementwise fp32 -> (hi,lo) bf16 split
// ---------------------------------------------------------------
__global__ __launch_bounds__(256) void conv_hl(const float* __restrict__ in,
                                               unsigned short* __restrict__ hi,
                                               unsigned short* __restrict__ lo, int n4) {
    int i = blockIdx.x * 256 + threadIdx.x;
    if (i >= n4) return;
    float4 v = ((const float4*)in)[i];
    ushort4 h, l;
    h.x = f2bf(v.x); l.x = f2bf(v.x - bf2f(h.x));
    h.y = f2bf(v.y); l.y = f2bf(v.y - bf2f(h.y));
    h.z = f2bf(v.z); l.z = f2bf(v.z - bf2f(h.z));
    h.w = f2bf(v.w); l.w = f2bf(v.w - bf2f(h.w));
    ((ushort4*)hi)[i] = h;
    ((ushort4*)lo)[i] = l;
}

// ---------------------------------------------------------------
// transpose + split: in[K][Nn] fp32 -> hi/lo [Nn][K] bf16
// ---------------------------------------------------------------
__global__ __launch_bounds__(256) void convT_hl(const float* __restrict__ in,
                                                unsigned short* __restrict__ hi,
                                                unsigned short* __restrict__ lo,
                                                int K, int Nn) {
    int k = blockIdx.x * 64 + (threadIdx.x & 63);
    int n = blockIdx.y * 4 + (threadIdx.x >> 6);
    float v = in[(size_t)k * Nn + n];
    unsigned short h = f2bf(v);
    hi[(size_t)n * K + k] = h;
    lo[(size_t)n * K + k] = f2bf(v - bf2f(h));
}

// ---------------------------------------------------------------
// split-bf16 MFMA GEMM (3M): C = A*B^T (+bias), fp32-accurate
// A hi/lo: [M][K] bf16 ; Bt hi/lo: [Nn][K] bf16 ; C: [M][Nn] fp32
// 128x128 tile, BK=32, 256 threads (4 waves, 2x2 of 64x64),
// 16x16x32 MFMA, fragment-contiguous LDS [kg][row][8].
// ---------------------------------------------------------------
__global__ __launch_bounds__(256) void gemm_mfma(const unsigned short* __restrict__ Ahi,
                                                 const unsigned short* __restrict__ Alo,
                                                 const unsigned short* __restrict__ Bhi,
                                                 const unsigned short* __restrict__ Blo,
                                                 const float* __restrict__ bias,
                                                 float* __restrict__ Cout,
                                                 int K, int Nn) {
    __shared__ bf16x8 AhS[512], AlS[512], BhS[512], BlS[512];   // 4 x 8KB
    int tid = threadIdx.x;
    int wv = tid >> 6, lane = tid & 63;
    int m0 = blockIdx.y * 128, n0 = blockIdx.x * 128;
    int wm = (wv >> 1) * 64, wn = (wv & 1) * 64;

    f32x4 acc[4][4];
    #pragma unroll
    for (int a = 0; a < 4; ++a)
        #pragma unroll
        for (int b = 0; b < 4; ++b) acc[a][b] = (f32x4){0.f, 0.f, 0.f, 0.f};

    int fr = lane & 15, fkg = lane >> 4;

    for (int k0 = 0; k0 < K; k0 += 32) {
        // stage 4 buffers of 128 rows x 32 k (8KB each) via async 16B loads
        #pragma unroll
        for (int c2 = 0; c2 < 2; ++c2) {
            int chunk = wv * 2 + c2;          // 0..7
            int g = chunk * 64 + lane;        // 0..511
            int kg = g >> 7, row = g & 127;
            size_t ao = (size_t)(m0 + row) * K + k0 + kg * 8;
            size_t bo = (size_t)(n0 + row) * K + k0 + kg * 8;
            gll16(Ahi + ao, &AhS[chunk * 64]);
            gll16(Alo + ao, &AlS[chunk * 64]);
            gll16(Bhi + bo, &BhS[chunk * 64]);
            gll16(Blo + bo, &BlS[chunk * 64]);
        }
        __syncthreads();

        bf16x8 ah[4], al[4], bh[4], bl[4];
        #pragma unroll
        for (int t = 0; t < 4; ++t) {
            ah[t] = AhS[fkg * 128 + wm + t * 16 + fr];
            al[t] = AlS[fkg * 128 + wm + t * 16 + fr];
            bh[t] = BhS[fkg * 128 + wn + t * 16 + fr];
            bl[t] = BlS[fkg * 128 + wn + t * 16 + fr];
        }
        #pragma unroll
        for (int mi = 0; mi < 4; ++mi)
            #pragma unroll
            for (int ni = 0; ni < 4; ++ni) {
                acc[mi][ni] = __builtin_amdgcn_mfma_f32_16x16x32_bf16(ah[mi], bh[ni], acc[mi][ni], 0, 0, 0);
                acc[mi][ni] = __builtin_amdgcn_mfma_f32_16x16x32_bf16(ah[mi], bl[ni], acc[mi][ni], 0, 0, 0);
                acc[mi][ni] = __builtin_amdgcn_mfma_f32_16x16x32_bf16(al[mi], bh[ni], acc[mi][ni], 0, 0, 0);
            }
        __syncthreads();
    }

    // epilogue: C/D layout col=lane&15, row=(lane>>4)*4+reg
    int cl = lane & 15, rq = (lane >> 4) * 4;
    #pragma unroll
    for (int ni = 0; ni < 4; ++ni) {
        int cc = n0 + wn + ni * 16 + cl;
        float bv = bias ? bias[cc] : 0.0f;
        #pragma unroll
        for (int mi = 0; mi < 4; ++mi) {
            int rb = m0 + wm + mi * 16 + rq;
            #pragma unroll
            for (int r = 0; r < 4; ++r)
                Cout[(size_t)(rb + r) * Nn + cc] = acc[mi][ni][r] + bv;
        }
    }
}

// ---------------------------------------------------------------
// per-(b,h): q_mean, k_mean, sum_v
// ---------------------------------------------------------------
__global__ __launch_bounds__(256) void stats_kernel(const float* __restrict__ qkv,
                                                    float* qmean, float* kmean, float* sv) {
    int bh = blockIdx.x; int b = bh >> 3; int h = bh & 7;
    int tid = threadIdx.x; int d = tid & 63; int g = tid >> 6;
    const float* base = qkv + (size_t)b * Nseq * QKVC + h * Dh + d;
    float sq = 0.f, sk = 0.f, svv = 0.f;
    for (int n = g; n < Nseq; n += 4) {
        const float* p = base + (size_t)n * QKVC;
        sq += p[0]; sk += p[512]; svv += p[1024];
    }
    __shared__ float red[3][4][64];
    red[0][g][d] = sq; red[1][g][d] = sk; red[2][g][d] = svv;
    __syncthreads();
    if (tid < 64) {
        float a  = red[0][0][d] + red[0][1][d] + red[0][2][d] + red[0][3][d];
        float k2 = red[1][0][d] + red[1][1][d] + red[1][2][d] + red[1][3][d];
        float v2 = red[2][0][d] + red[2][1][d] + red[2][2][d] + red[2][3][d];
        qmean[bh * 64 + d] = a  * (1.0f / Nseq);
        kmean[bh * 64 + d] = k2 * (1.0f / Nseq);
        sv[bh * 64 + d]    = v2;
    }
}

// ---------------------------------------------------------------
// row score_i = scale*q_i.k_mean ; col score_j = scale*q_mean.k_j
// ---------------------------------------------------------------
__global__ __launch_bounds__(256) void score_kernel(const float* __restrict__ qkv,
                                                    const float* __restrict__ qmean,
                                                    const float* __restrict__ kmean,
                                                    float* rsc, float* csc) {
    int bh = blockIdx.x; int b = bh >> 3, h = bh & 7;
    int i = blockIdx.y * 256 + threadIdx.x;
    __shared__ float qm[64], km[64];
    if (threadIdx.x < 64) {
        qm[threadIdx.x] = qmean[bh * 64 + threadIdx.x];
        km[threadIdx.x] = kmean[bh * 64 + threadIdx.x];
    }
    __syncthreads();
    const float* qp = qkv + (size_t)b * Nseq * QKVC + (size_t)i * QKVC + h * Dh;
    float r = 0.f, c = 0.f;
    #pragma unroll 8
    for (int d = 0; d < 64; ++d) { r += qp[d] * km[d]; c += qp[512 + d] * qm[d]; }
    rsc[(size_t)bh * Nseq + i] = r * 0.125f;
    csc[(size_t)bh * Nseq + i] = c * 0.125f;
}

// ---------------------------------------------------------------
// top-256 of 2048 by rank counting on packed (value,index) keys.
// ---------------------------------------------------------------
__global__ __launch_bounds__(256) void topk_kernel(const float* __restrict__ rsc,
                                                   const float* __restrict__ csc,
                                                   int* ridx, int* cidx) {
    int selid = blockIdx.y;
    int bh = selid >> 1, which = selid & 1;
    const float* sin = which ? (csc + (size_t)bh * Nseq) : (rsc + (size_t)bh * Nseq);
    int* outp = which ? (cidx + bh * TK) : (ridx + bh * TK);
    __shared__ unsigned long long keys[Nseq];
    int tid = threadIdx.x;
    for (int i = tid; i < Nseq; i += 256) {
        unsigned u = __float_as_uint(sin[i]);
        u = (u & 0x80000000u) ? ~u : (u | 0x80000000u);
        keys[i] = ((unsigned long long)u << 32) | (unsigned)(Nseq - 1 - i);
    }
    __syncthreads();
    int i = blockIdx.x * 256 + tid;
    unsigned long long ki = keys[i];
    int rank = 0;
    #pragma unroll 8
    for (int j = 0; j < Nseq; ++j) rank += (keys[j] > ki) ? 1 : 0;
    if (rank < TK) outp[rank] = i;
}

// ---------------------------------------------------------------
// sum of v over the 256 selected columns
// ---------------------------------------------------------------
__global__ __launch_bounds__(256) void svsel_kernel(const float* __restrict__ qkv,
                                                    const int* __restrict__ cidx,
                                                    float* svsel) {
    int bh = blockIdx.x; int b = bh >> 3, h = bh & 7;
    int tid = threadIdx.x; int d = tid & 63, g = tid >> 6;
    float sum = 0.f;
    for (int j = g; j < TK; j += 4) {
        int col = cidx[bh * TK + j];
        sum += qkv[(size_t)b * Nseq * QKVC + (size_t)col * QKVC + 1024 + h * Dh + d];
    }
    __shared__ float red[4][64];
    red[g][d] = sum;
    __syncthreads();
    if (tid < 64) svsel[bh * 64 + d] = red[0][d] + red[1][d] + red[2][d] + red[3][d];
}

// ---------------------------------------------------------------
// E kernel: 256x256 selected block scores + exp. grid (BH, 8).
// ---------------------------------------------------------------
__global__ __launch_bounds__(256) void attn_e_kernel(const float* __restrict__ qkv,
                                                     const int* __restrict__ ridx,
                                                     const int* __restrict__ cidx,
                                                     float* __restrict__ Ebuf,
                                                     float* um, float* invZ) {
    int bh = blockIdx.x; int b = bh >> 3, h = bh & 7;
    int rblk = blockIdx.y;
    __shared__ float Kt[64 * 256];     // Kt[d*256 + j]
    int tid = threadIdx.x;
    {
        int j = tid;
        int col = cidx[bh * TK + j];
        const float* kp = qkv + (size_t)b * Nseq * QKVC + (size_t)col * QKVC + 512 + h * Dh;
        #pragma unroll 8
        for (int d = 0; d < 64; ++d) Kt[d * 256 + j] = kp[d];
    }
    __syncthreads();
    int wave = tid >> 6, lane = tid & 63;
    for (int rr = 0; rr < 8; ++rr) {
        int i = rblk * 32 + wave * 8 + rr;
        int row = ridx[bh * TK + i];
        float qv = qkv[(size_t)b * Nseq * QKVC + (size_t)row * QKVC + h * Dh + lane];
        float s0 = 0.f, s1 = 0.f, s2 = 0.f, s3 = 0.f;
        #pragma unroll 8
        for (int d = 0; d < 64; ++d) {
            float qd = __shfl(qv, d, 64);
            const float* kr = &Kt[d * 256 + lane];
            s0 += qd * kr[0];
            s1 += qd * kr[64];
            s2 += qd * kr[128];
            s3 += qd * kr[192];
        }
        s0 *= 0.125f; s1 *= 0.125f; s2 *= 0.125f; s3 *= 0.125f;
        float mx = fmaxf(fmaxf(s0, s1), fmaxf(s2, s3));
        #pragma unroll
        for (int off = 32; off; off >>= 1) mx = fmaxf(mx, __shfl_xor(mx, off, 64));
        mx = fmaxf(mx, 0.0f);
        float e0 = __expf(s0 - mx), e1 = __expf(s1 - mx);
        float e2 = __expf(s2 - mx), e3 = __expf(s3 - mx);
        float zs = e0 + e1 + e2 + e3;
        #pragma unroll
        for (int off = 32; off; off >>= 1) zs += __shfl_xor(zs, off, 64);
        float em = __expf(-mx);
        float Z = (float)(Nseq - TK) * em + zs;
        float* ep = Ebuf + ((size_t)bh * TK + i) * TK;
        ep[lane] = e0; ep[lane + 64] = e1; ep[lane + 128] = e2; ep[lane + 192] = e3;
        if (lane == 0) { um[bh * TK + i] = em; invZ[bh * TK + i] = 1.0f / Z; }
    }
}

// ---------------------------------------------------------------
// uniform rows -> hctx hi/lo bf16
// ---------------------------------------------------------------
__global__ __launch_bounds__(256) void fill_uniform(const float* __restrict__ sv,
                                                    unsigned short* __restrict__ hh,
                                                    unsigned short* __restrict__ hl) {
    int idx = blockIdx.x * 256 + threadIdx.x;
    int c = idx & 511;
    int b = idx >> 20;
    int head = c >> 6, d = c & 63;
    float v = sv[((b << 3) + head) * 64 + d] * (1.0f / Nseq);
    unsigned short hv = f2bf(v);
    hh[idx] = hv;
    hl[idx] = f2bf(v - bf2f(hv));
}

// ---------------------------------------------------------------
// AV kernel: selected rows. grid (BH, 8). writes hctx hi/lo bf16.
// ---------------------------------------------------------------
__global__ __launch_bounds__(256) void attn_av_kernel(const float* __restrict__ qkv,
                                                      const int* __restrict__ ridx,
                                                      const int* __restrict__ cidx,
                                                      const float* __restrict__ Ebuf,
                                                      const float* __restrict__ um,
                                                      const float* __restrict__ invZ,
                                                      const float* __restrict__ sv,
                                                      const float* __restrict__ svsel,
                                                      unsigned short* __restrict__ hctx_hi,
                                                      unsigned short* __restrict__ hctx_lo) {
    int bh = blockIdx.x; int b = bh >> 3, h = bh & 7;
    int rblk = blockIdx.y;
    __shared__ float Vs[TK * 64];
    int tid = threadIdx.x;
    size_t vbase = (size_t)b * Nseq * QKVC + 1024 + h * Dh;
    for (int idx = tid; idx < TK * 64; idx += 256) {
        int j = idx >> 6, d = idx & 63;
        Vs[idx] = qkv[vbase + (size_t)cidx[bh * TK + j] * QKVC + d];
    }
    __syncthreads();
    int wave = tid >> 6, lane = tid & 63;
    float sadj = sv[bh * 64 + lane] - svsel[bh * 64 + lane];
    for (int rr = 0; rr < 8; ++rr) {
        int i = rblk * 32 + wave * 8 + rr;
        const float* ep = Ebuf + ((size_t)bh * TK + i) * TK;
        float e0 = ep[lane], e1 = ep[lane + 64], e2 = ep[lane + 128], e3 = ep[lane + 192];
        float acc = 0.f;
        #pragma unroll 4
        for (int j = 0; j < 64; ++j) {
            float w0 = __shfl(e0, j, 64), w1 = __shfl(e1, j, 64);
            float w2 = __shfl(e2, j, 64), w3 = __shfl(e3, j, 64);
            acc += w0 * Vs[j * 64 + lane];
            acc += w1 * Vs[(j + 64) * 64 + lane];
            acc += w2 * Vs[(j + 128) * 64 + lane];
            acc += w3 * Vs[(j + 192) * 64 + lane];
        }
        float outv = (um[bh * TK + i] * sadj + acc) * invZ[bh * TK + i];
        int row = ridx[bh * TK + i];
        size_t o = (size_t)b * Nseq * Cdim + (size_t)row * Cdim + h * Dh + lane;
        unsigned short hv = f2bf(outv);
        hctx_hi[o] = hv;
        hctx_lo[o] = f2bf(outv - bf2f(hv));
    }
}

extern "C" void kernel_launch(void* const* d_in, const int* in_sizes, int n_in,
                              void* d_out, int out_size, void* d_ws, size_t ws_size,
                              hipStream_t stream) {
    const float* x     = (const float*)d_in[0];
    const float* w_qkv = (const float*)d_in[1];
    const float* w_out = (const float*)d_in[2];
    const float* b_out = (const float*)d_in[3];
    float* out = (float*)d_out;

    float* ws = (float*)d_ws;
    float* qkv = ws;                                                   // 12,582,912 f
    unsigned short* wqT_hi = (unsigned short*)(qkv + (size_t)Bsz * Nseq * QKVC);
    unsigned short* wqT_lo = wqT_hi + (size_t)512 * 1536;
    unsigned short* woT_hi = wqT_lo + (size_t)512 * 1536;
    unsigned short* woT_lo = woT_hi + (size_t)512 * 512;
    float* qmean = (float*)(woT_lo + (size_t)512 * 512);
    float* kmean = qmean + BH * Dh;
    float* sv    = kmean + BH * Dh;
    float* svsel = sv + BH * Dh;
    float* rsc   = svsel + BH * Dh;
    float* csc   = rsc + (size_t)BH * Nseq;
    int*   ridx  = (int*)(csc + (size_t)BH * Nseq);
    int*   cidx  = ridx + BH * TK;
    float* um    = (float*)(cidx + BH * TK);
    float* invZ  = um + BH * TK;
    float* region = invZ + BH * TK;
    // aliases: xhi/xlo live only until gemm1; Ebuf/hctx written after.
    unsigned short* xhi = (unsigned short*)region;                     // 4,194,304 ush
    unsigned short* xlo = xhi + (size_t)MROWS * Cdim;
    float* Ebuf = region;                                              // 2,097,152 f
    unsigned short* hctx_hi = (unsigned short*)(Ebuf + (size_t)BH * TK * TK);
    unsigned short* hctx_lo = hctx_hi + (size_t)MROWS * Cdim;

    // 0. split conversions
    conv_hl<<<(MROWS * Cdim / 4 + 255) / 256, 256, 0, stream>>>(x, xhi, xlo, MROWS * Cdim / 4);
    convT_hl<<<dim3(8, 384), 256, 0, stream>>>(w_qkv, wqT_hi, wqT_lo, 512, 1536);
    convT_hl<<<dim3(8, 128), 256, 0, stream>>>(w_out, woT_hi, woT_lo, 512, 512);
    // 1. qkv = x @ w_qkv via split-bf16 MFMA (fp32-accurate)
    gemm_mfma<<<dim3(QKVC / 128, MROWS / 128), 256, 0, stream>>>(xhi, xlo, wqT_hi, wqT_lo,
                                                                 nullptr, qkv, Cdim, QKVC);
    // 2. per-(b,h) means / sums
    stats_kernel<<<BH, 256, 0, stream>>>(qkv, qmean, kmean, sv);
    // 3. rank-1 row/col scores
    score_kernel<<<dim3(BH, Nseq / 256), 256, 0, stream>>>(qkv, qmean, kmean, rsc, csc);
    // 4. top-256 selections
    topk_kernel<<<dim3(Nseq / 256, BH * 2), 256, 0, stream>>>(rsc, csc, ridx, cidx);
    // 5. sum of v over selected cols
    svsel_kernel<<<BH, 256, 0, stream>>>(qkv, cidx, svsel);
    // 6. scores+exp for selected 256x256 block
    attn_e_kernel<<<dim3(BH, 8), 256, 0, stream>>>(qkv, ridx, cidx, Ebuf, um, invZ);
    // 7. uniform rows
    fill_uniform<<<(Bsz * Nseq * Cdim) / 256, 256, 0, stream>>>(sv, hctx_hi, hctx_lo);
    // 8. selected rows
    attn_av_kernel<<<dim3(BH, 8), 256, 0, stream>>>(qkv, ridx, cidx, Ebuf, um, invZ, sv, svsel,
                                                    hctx_hi, hctx_lo);
    // 9. out = hctx @ w_out + b_out via split-bf16 MFMA
    gemm_mfma<<<dim3(Cdim / 128, MROWS / 128), 256, 0, stream>>>(hctx_hi, hctx_lo, woT_hi, woT_lo,
                                                                 b_out, out, Cdim, Cdim);
}

// Round 3
// 312.819 us; speedup vs baseline: 2.0401x; 1.5270x over previous
//
#include <hip/hip_runtime.h>
#include <math.h>

#define Bsz 4
#define Nseq 2048
#define Cdim 512
#define Hn 8
#define Dh 64
#define TK 256
#define BH (Bsz*Hn)          // 32
#define MROWS (Bsz*Nseq)     // 8192
#define QKVC 1536

typedef __attribute__((ext_vector_type(8))) short bf16x8;
typedef __attribute__((ext_vector_type(4))) float f32x4;

__device__ __forceinline__ unsigned short f2bf(float x) {
    unsigned u = __float_as_uint(x);
    unsigned r = (u + 0x7fffu + ((u >> 16) & 1u)) >> 16;   // round-to-nearest-even
    return (unsigned short)r;
}
__device__ __forceinline__ float bf2f(unsigned short h) {
    return __uint_as_float((unsigned)h << 16);
}

__device__ __forceinline__ void gll16(const void* g, void* l) {
    __builtin_amdgcn_global_load_lds((const __attribute__((address_space(1))) unsigned int*)g,
                                     (__attribute__((address_space(3))) unsigned int*)l,
                                     16, 0, 0);
}

// ---------------------------------------------------------------
// elementwise fp32 -> (hi,lo) bf16 split
// ---------------------------------------------------------------
__global__ __launch_bounds__(256) void conv_hl(const float* __restrict__ in,
                                               unsigned short* __restrict__ hi,
                                               unsigned short* __restrict__ lo, int n4) {
    int i = blockIdx.x * 256 + threadIdx.x;
    if (i >= n4) return;
    float4 v = ((const float4*)in)[i];
    ushort4 h, l;
    h.x = f2bf(v.x); l.x = f2bf(v.x - bf2f(h.x));
    h.y = f2bf(v.y); l.y = f2bf(v.y - bf2f(h.y));
    h.z = f2bf(v.z); l.z = f2bf(v.z - bf2f(h.z));
    h.w = f2bf(v.w); l.w = f2bf(v.w - bf2f(h.w));
    ((ushort4*)hi)[i] = h;
    ((ushort4*)lo)[i] = l;
}

// ---------------------------------------------------------------
// transpose + split: in[K][Nn] fp32 -> hi/lo [Nn][K] bf16
// ---------------------------------------------------------------
__global__ __launch_bounds__(256) void convT_hl(const float* __restrict__ in,
                                                unsigned short* __restrict__ hi,
                                                unsigned short* __restrict__ lo,
                                                int K, int Nn) {
    int k = blockIdx.x * 64 + (threadIdx.x & 63);
    int n = blockIdx.y * 4 + (threadIdx.x >> 6);
    float v = in[(size_t)k * Nn + n];
    unsigned short h = f2bf(v);
    hi[(size_t)n * K + k] = h;
    lo[(size_t)n * K + k] = f2bf(v - bf2f(h));
}

// ---------------------------------------------------------------
// split-bf16 MFMA GEMM (3M): C = A*B^T (+bias), fp32-accurate
// ---------------------------------------------------------------
__global__ __launch_bounds__(256) void gemm_mfma(const unsigned short* __restrict__ Ahi,
                                                 const unsigned short* __restrict__ Alo,
                                                 const unsigned short* __restrict__ Bhi,
                                                 const unsigned short* __restrict__ Blo,
                                                 const float* __restrict__ bias,
                                                 float* __restrict__ Cout,
                                                 int K, int Nn) {
    __shared__ bf16x8 AhS[512], AlS[512], BhS[512], BlS[512];   // 4 x 8KB
    int tid = threadIdx.x;
    int wv = tid >> 6, lane = tid & 63;
    int m0 = blockIdx.y * 128, n0 = blockIdx.x * 128;
    int wm = (wv >> 1) * 64, wn = (wv & 1) * 64;

    f32x4 acc[4][4];
    #pragma unroll
    for (int a = 0; a < 4; ++a)
        #pragma unroll
        for (int b = 0; b < 4; ++b) acc[a][b] = (f32x4){0.f, 0.f, 0.f, 0.f};

    int fr = lane & 15, fkg = lane >> 4;

    for (int k0 = 0; k0 < K; k0 += 32) {
        #pragma unroll
        for (int c2 = 0; c2 < 2; ++c2) {
            int chunk = wv * 2 + c2;          // 0..7
            int g = chunk * 64 + lane;        // 0..511
            int kg = g >> 7, row = g & 127;
            size_t ao = (size_t)(m0 + row) * K + k0 + kg * 8;
            size_t bo = (size_t)(n0 + row) * K + k0 + kg * 8;
            gll16(Ahi + ao, &AhS[chunk * 64]);
            gll16(Alo + ao, &AlS[chunk * 64]);
            gll16(Bhi + bo, &BhS[chunk * 64]);
            gll16(Blo + bo, &BlS[chunk * 64]);
        }
        __syncthreads();

        bf16x8 ah[4], al[4], bh[4], bl[4];
        #pragma unroll
        for (int t = 0; t < 4; ++t) {
            ah[t] = AhS[fkg * 128 + wm + t * 16 + fr];
            al[t] = AlS[fkg * 128 + wm + t * 16 + fr];
            bh[t] = BhS[fkg * 128 + wn + t * 16 + fr];
            bl[t] = BlS[fkg * 128 + wn + t * 16 + fr];
        }
        #pragma unroll
        for (int mi = 0; mi < 4; ++mi)
            #pragma unroll
            for (int ni = 0; ni < 4; ++ni) {
                acc[mi][ni] = __builtin_amdgcn_mfma_f32_16x16x32_bf16(ah[mi], bh[ni], acc[mi][ni], 0, 0, 0);
                acc[mi][ni] = __builtin_amdgcn_mfma_f32_16x16x32_bf16(ah[mi], bl[ni], acc[mi][ni], 0, 0, 0);
                acc[mi][ni] = __builtin_amdgcn_mfma_f32_16x16x32_bf16(al[mi], bh[ni], acc[mi][ni], 0, 0, 0);
            }
        __syncthreads();
    }

    int cl = lane & 15, rq = (lane >> 4) * 4;
    #pragma unroll
    for (int ni = 0; ni < 4; ++ni) {
        int cc = n0 + wn + ni * 16 + cl;
        float bv = bias ? bias[cc] : 0.0f;
        #pragma unroll
        for (int mi = 0; mi < 4; ++mi) {
            int rb = m0 + wm + mi * 16 + rq;
            #pragma unroll
            for (int r = 0; r < 4; ++r)
                Cout[(size_t)(rb + r) * Nn + cc] = acc[mi][ni][r] + bv;
        }
    }
}

// ---------------------------------------------------------------
// stats stage 1: per-(b,h), per-128-row-chunk partial sums of q,k,v.
// grid (BH, 16). part[((bh*16+chunk)*3+comp)*64+d]
// ---------------------------------------------------------------
__global__ __launch_bounds__(256) void stats_part(const float* __restrict__ qkv,
                                                  float* __restrict__ part) {
    int bh = blockIdx.x; int b = bh >> 3; int h = bh & 7;
    int chunk = blockIdx.y;
    int tid = threadIdx.x; int d = tid & 63; int g = tid >> 6;
    const float* base = qkv + (size_t)b * Nseq * QKVC + h * Dh + d;
    float sq = 0.f, sk = 0.f, svv = 0.f;
    int n0 = chunk * 128;
    for (int n = n0 + g; n < n0 + 128; n += 4) {
        const float* p = base + (size_t)n * QKVC;
        sq += p[0]; sk += p[512]; svv += p[1024];
    }
    __shared__ float red[3][4][64];
    red[0][g][d] = sq; red[1][g][d] = sk; red[2][g][d] = svv;
    __syncthreads();
    if (tid < 64) {
        size_t o = ((size_t)(bh * 16 + chunk) * 3) * 64 + d;
        part[o]       = red[0][0][d] + red[0][1][d] + red[0][2][d] + red[0][3][d];
        part[o + 64]  = red[1][0][d] + red[1][1][d] + red[1][2][d] + red[1][3][d];
        part[o + 128] = red[2][0][d] + red[2][1][d] + red[2][2][d] + red[2][3][d];
    }
}

// ---------------------------------------------------------------
// stats stage 2: sum 16 chunks -> qmean, kmean, sv. grid BH.
// ---------------------------------------------------------------
__global__ __launch_bounds__(256) void stats_final(const float* __restrict__ part,
                                                   float* qmean, float* kmean, float* sv) {
    int bh = blockIdx.x;
    int tid = threadIdx.x;
    if (tid >= 192) return;
    int comp = tid >> 6, d = tid & 63;
    float s = 0.f;
    for (int c = 0; c < 16; ++c)
        s += part[((size_t)(bh * 16 + c) * 3 + comp) * 64 + d];
    if (comp == 0)      qmean[bh * 64 + d] = s * (1.0f / Nseq);
    else if (comp == 1) kmean[bh * 64 + d] = s * (1.0f / Nseq);
    else                sv[bh * 64 + d]    = s;
}

// ---------------------------------------------------------------
// row score_i = scale*q_i.k_mean ; col score_j = scale*q_mean.k_j
// ---------------------------------------------------------------
__global__ __launch_bounds__(256) void score_kernel(const float* __restrict__ qkv,
                                                    const float* __restrict__ qmean,
                                                    const float* __restrict__ kmean,
                                                    float* rsc, float* csc) {
    int bh = blockIdx.x; int b = bh >> 3, h = bh & 7;
    int i = blockIdx.y * 256 + threadIdx.x;
    __shared__ float qm[64], km[64];
    if (threadIdx.x < 64) {
        qm[threadIdx.x] = qmean[bh * 64 + threadIdx.x];
        km[threadIdx.x] = kmean[bh * 64 + threadIdx.x];
    }
    __syncthreads();
    const float* qp = qkv + (size_t)b * Nseq * QKVC + (size_t)i * QKVC + h * Dh;
    float r = 0.f, c = 0.f;
    #pragma unroll 8
    for (int d = 0; d < 64; ++d) { r += qp[d] * km[d]; c += qp[512 + d] * qm[d]; }
    rsc[(size_t)bh * Nseq + i] = r * 0.125f;
    csc[(size_t)bh * Nseq + i] = c * 0.125f;
}

// ---------------------------------------------------------------
// top-256 of 2048 by rank counting on packed (value,index) keys.
// ---------------------------------------------------------------
__global__ __launch_bounds__(256) void topk_kernel(const float* __restrict__ rsc,
                                                   const float* __restrict__ csc,
                                                   int* ridx, int* cidx) {
    int selid = blockIdx.y;
    int bh = selid >> 1, which = selid & 1;
    const float* sin = which ? (csc + (size_t)bh * Nseq) : (rsc + (size_t)bh * Nseq);
    int* outp = which ? (cidx + bh * TK) : (ridx + bh * TK);
    __shared__ unsigned long long keys[Nseq];
    int tid = threadIdx.x;
    for (int i = tid; i < Nseq; i += 256) {
        unsigned u = __float_as_uint(sin[i]);
        u = (u & 0x80000000u) ? ~u : (u | 0x80000000u);
        keys[i] = ((unsigned long long)u << 32) | (unsigned)(Nseq - 1 - i);
    }
    __syncthreads();
    int i = blockIdx.x * 256 + tid;
    unsigned long long ki = keys[i];
    int rank = 0;
    #pragma unroll 8
    for (int j = 0; j < Nseq; ++j) rank += (keys[j] > ki) ? 1 : 0;
    if (rank < TK) outp[rank] = i;
}

// ---------------------------------------------------------------
// E kernel: 256x256 selected block scores + exp. grid (BH, 8).
// ---------------------------------------------------------------
__global__ __launch_bounds__(256) void attn_e_kernel(const float* __restrict__ qkv,
                                                     const int* __restrict__ ridx,
                                                     const int* __restrict__ cidx,
                                                     float* __restrict__ Ebuf,
                                                     float* um, float* invZ) {
    int bh = blockIdx.x; int b = bh >> 3, h = bh & 7;
    int rblk = blockIdx.y;
    __shared__ float Kt[64 * 256];     // Kt[d*256 + j]
    int tid = threadIdx.x;
    {
        int j = tid;
        int col = cidx[bh * TK + j];
        const float* kp = qkv + (size_t)b * Nseq * QKVC + (size_t)col * QKVC + 512 + h * Dh;
        #pragma unroll 8
        for (int d = 0; d < 64; ++d) Kt[d * 256 + j] = kp[d];
    }
    __syncthreads();
    int wave = tid >> 6, lane = tid & 63;
    for (int rr = 0; rr < 8; ++rr) {
        int i = rblk * 32 + wave * 8 + rr;
        int row = ridx[bh * TK + i];
        float qv = qkv[(size_t)b * Nseq * QKVC + (size_t)row * QKVC + h * Dh + lane];
        float s0 = 0.f, s1 = 0.f, s2 = 0.f, s3 = 0.f;
        #pragma unroll 8
        for (int d = 0; d < 64; ++d) {
            float qd = __shfl(qv, d, 64);
            const float* kr = &Kt[d * 256 + lane];
            s0 += qd * kr[0];
            s1 += qd * kr[64];
            s2 += qd * kr[128];
            s3 += qd * kr[192];
        }
        s0 *= 0.125f; s1 *= 0.125f; s2 *= 0.125f; s3 *= 0.125f;
        float mx = fmaxf(fmaxf(s0, s1), fmaxf(s2, s3));
        #pragma unroll
        for (int off = 32; off; off >>= 1) mx = fmaxf(mx, __shfl_xor(mx, off, 64));
        mx = fmaxf(mx, 0.0f);
        float e0 = __expf(s0 - mx), e1 = __expf(s1 - mx);
        float e2 = __expf(s2 - mx), e3 = __expf(s3 - mx);
        float zs = e0 + e1 + e2 + e3;
        #pragma unroll
        for (int off = 32; off; off >>= 1) zs += __shfl_xor(zs, off, 64);
        float em = __expf(-mx);
        float Z = (float)(Nseq - TK) * em + zs;
        float* ep = Ebuf + ((size_t)bh * TK + i) * TK;
        ep[lane] = e0; ep[lane + 64] = e1; ep[lane + 128] = e2; ep[lane + 192] = e3;
        if (lane == 0) { um[bh * TK + i] = em; invZ[bh * TK + i] = 1.0f / Z; }
    }
}

// ---------------------------------------------------------------
// uniform rows -> hctx hi/lo bf16
// ---------------------------------------------------------------
__global__ __launch_bounds__(256) void fill_uniform(const float* __restrict__ sv,
                                                    unsigned short* __restrict__ hh,
                                                    unsigned short* __restrict__ hl) {
    int idx = blockIdx.x * 256 + threadIdx.x;
    int c = idx & 511;
    int b = idx >> 20;
    int head = c >> 6, d = c & 63;
    float v = sv[((b << 3) + head) * 64 + d] * (1.0f / Nseq);
    unsigned short hv = f2bf(v);
    hh[idx] = hv;
    hl[idx] = f2bf(v - bf2f(hv));
}

// ---------------------------------------------------------------
// AV kernel: selected rows. grid (BH, 8). svsel computed in-LDS.
// ---------------------------------------------------------------
__global__ __launch_bounds__(256) void attn_av_kernel(const float* __restrict__ qkv,
                                                      const int* __restrict__ ridx,
                                                      const int* __restrict__ cidx,
                                                      const float* __restrict__ Ebuf,
                                                      const float* __restrict__ um,
                                                      const float* __restrict__ invZ,
                                                      const float* __restrict__ sv,
                                                      unsigned short* __restrict__ hctx_hi,
                                                      unsigned short* __restrict__ hctx_lo) {
    int bh = blockIdx.x; int b = bh >> 3, h = bh & 7;
    int rblk = blockIdx.y;
    __shared__ float Vs[TK * 64];
    int tid = threadIdx.x;
    size_t vbase = (size_t)b * Nseq * QKVC + 1024 + h * Dh;
    for (int idx = tid; idx < TK * 64; idx += 256) {
        int j = idx >> 6, d = idx & 63;
        Vs[idx] = qkv[vbase + (size_t)cidx[bh * TK + j] * QKVC + d];
    }
    __syncthreads();
    int wave = tid >> 6, lane = tid & 63;
    // svsel[lane] redundantly per wave from LDS (removes svsel_kernel)
    float ssel = 0.f;
    #pragma unroll 8
    for (int j = 0; j < TK; ++j) ssel += Vs[j * 64 + lane];
    float sadj = sv[bh * 64 + lane] - ssel;
    for (int rr = 0; rr < 8; ++rr) {
        int i = rblk * 32 + wave * 8 + rr;
        const float* ep = Ebuf + ((size_t)bh * TK + i) * TK;
        float e0 = ep[lane], e1 = ep[lane + 64], e2 = ep[lane + 128], e3 = ep[lane + 192];
        float acc = 0.f;
        #pragma unroll 4
        for (int j = 0; j < 64; ++j) {
            float w0 = __shfl(e0, j, 64), w1 = __shfl(e1, j, 64);
            float w2 = __shfl(e2, j, 64), w3 = __shfl(e3, j, 64);
            acc += w0 * Vs[j * 64 + lane];
            acc += w1 * Vs[(j + 64) * 64 + lane];
            acc += w2 * Vs[(j + 128) * 64 + lane];
            acc += w3 * Vs[(j + 192) * 64 + lane];
        }
        float outv = (um[bh * TK + i] * sadj + acc) * invZ[bh * TK + i];
        int row = ridx[bh * TK + i];
        size_t o = (size_t)b * Nseq * Cdim + (size_t)row * Cdim + h * Dh + lane;
        unsigned short hv = f2bf(outv);
        hctx_hi[o] = hv;
        hctx_lo[o] = f2bf(outv - bf2f(hv));
    }
}

extern "C" void kernel_launch(void* const* d_in, const int* in_sizes, int n_in,
                              void* d_out, int out_size, void* d_ws, size_t ws_size,
                              hipStream_t stream) {
    const float* x     = (const float*)d_in[0];
    const float* w_qkv = (const float*)d_in[1];
    const float* w_out = (const float*)d_in[2];
    const float* b_out = (const float*)d_in[3];
    float* out = (float*)d_out;

    float* ws = (float*)d_ws;
    float* qkv = ws;                                                   // 12,582,912 f
    unsigned short* wqT_hi = (unsigned short*)(qkv + (size_t)Bsz * Nseq * QKVC);
    unsigned short* wqT_lo = wqT_hi + (size_t)512 * 1536;
    unsigned short* woT_hi = wqT_lo + (size_t)512 * 1536;
    unsigned short* woT_lo = woT_hi + (size_t)512 * 512;
    float* qmean = (float*)(woT_lo + (size_t)512 * 512);
    float* kmean = qmean + BH * Dh;
    float* sv    = kmean + BH * Dh;
    float* rsc   = sv + BH * Dh;
    float* csc   = rsc + (size_t)BH * Nseq;
    int*   ridx  = (int*)(csc + (size_t)BH * Nseq);
    int*   cidx  = ridx + BH * TK;
    float* um    = (float*)(cidx + BH * TK);
    float* invZ  = um + BH * TK;
    float* region = invZ + BH * TK;
    // aliases: xhi/xlo live only until gemm1; Ebuf/hctx written after.
    unsigned short* xhi = (unsigned short*)region;                     // 4,194,304 ush
    unsigned short* xlo = xhi + (size_t)MROWS * Cdim;
    float* Ebuf = region;                                              // 2,097,152 f
    unsigned short* hctx_hi = (unsigned short*)(Ebuf + (size_t)BH * TK * TK);
    unsigned short* hctx_lo = hctx_hi + (size_t)MROWS * Cdim;
    // stats partials alias rsc/csc (dead until score_kernel runs)
    float* part = rsc;                                                 // 98,304 f

    // 0. split conversions
    conv_hl<<<(MROWS * Cdim / 4 + 255) / 256, 256, 0, stream>>>(x, xhi, xlo, MROWS * Cdim / 4);
    convT_hl<<<dim3(8, 384), 256, 0, stream>>>(w_qkv, wqT_hi, wqT_lo, 512, 1536);
    convT_hl<<<dim3(8, 128), 256, 0, stream>>>(w_out, woT_hi, woT_lo, 512, 512);
    // 1. qkv = x @ w_qkv via split-bf16 MFMA (fp32-accurate)
    gemm_mfma<<<dim3(QKVC / 128, MROWS / 128), 256, 0, stream>>>(xhi, xlo, wqT_hi, wqT_lo,
                                                                 nullptr, qkv, Cdim, QKVC);
    // 2. per-(b,h) means / sums (two-stage for parallelism)
    stats_part<<<dim3(BH, 16), 256, 0, stream>>>(qkv, part);
    stats_final<<<BH, 256, 0, stream>>>(part, qmean, kmean, sv);
    // 3. rank-1 row/col scores
    score_kernel<<<dim3(BH, Nseq / 256), 256, 0, stream>>>(qkv, qmean, kmean, rsc, csc);
    // 4. top-256 selections
    topk_kernel<<<dim3(Nseq / 256, BH * 2), 256, 0, stream>>>(rsc, csc, ridx, cidx);
    // 5. scores+exp for selected 256x256 block
    attn_e_kernel<<<dim3(BH, 8), 256, 0, stream>>>(qkv, ridx, cidx, Ebuf, um, invZ);
    // 6. uniform rows
    fill_uniform<<<(Bsz * Nseq * Cdim) / 256, 256, 0, stream>>>(sv, hctx_hi, hctx_lo);
    // 7. selected rows (svsel folded in)
    attn_av_kernel<<<dim3(BH, 8), 256, 0, stream>>>(qkv, ridx, cidx, Ebuf, um, invZ, sv,
                                                    hctx_hi, hctx_lo);
    // 8. out = hctx @ w_out + b_out via split-bf16 MFMA
    gemm_mfma<<<dim3(Cdim / 128, MROWS / 128), 256, 0, stream>>>(hctx_hi, hctx_lo, woT_hi, woT_lo,
                                                                 b_out, out, Cdim, Cdim);
}

// Round 4
// 250.997 us; speedup vs baseline: 2.5426x; 1.2463x over previous
//
#include <hip/hip_runtime.h>
#include <math.h>

#define Bsz 4
#define Nseq 2048
#define Cdim 512
#define Hn 8
#define Dh 64
#define TK 256
#define BH (Bsz*Hn)          // 32
#define MROWS (Bsz*Nseq)     // 8192
#define QKVC 1536

typedef __attribute__((ext_vector_type(8))) short bf16x8;
typedef __attribute__((ext_vector_type(4))) float f32x4;

__device__ __forceinline__ unsigned short f2bf(float x) {
    unsigned u = __float_as_uint(x);
    unsigned r = (u + 0x7fffu + ((u >> 16) & 1u)) >> 16;   // round-to-nearest-even
    return (unsigned short)r;
}
__device__ __forceinline__ float bf2f(unsigned short h) {
    return __uint_as_float((unsigned)h << 16);
}

__device__ __forceinline__ void gll16(const void* g, void* l) {
    __builtin_amdgcn_global_load_lds((const __attribute__((address_space(1))) unsigned int*)g,
                                     (__attribute__((address_space(3))) unsigned int*)l,
                                     16, 0, 0);
}

// ---------------------------------------------------------------
// elementwise fp32 -> (hi,lo) bf16 split (for x)
// ---------------------------------------------------------------
__global__ __launch_bounds__(256) void conv_hl(const float* __restrict__ in,
                                               unsigned short* __restrict__ hi,
                                               unsigned short* __restrict__ lo, int n4) {
    int i = blockIdx.x * 256 + threadIdx.x;
    if (i >= n4) return;
    float4 v = ((const float4*)in)[i];
    ushort4 h, l;
    h.x = f2bf(v.x); l.x = f2bf(v.x - bf2f(h.x));
    h.y = f2bf(v.y); l.y = f2bf(v.y - bf2f(h.y));
    h.z = f2bf(v.z); l.z = f2bf(v.z - bf2f(h.z));
    h.w = f2bf(v.w); l.w = f2bf(v.w - bf2f(h.w));
    ((ushort4*)hi)[i] = h;
    ((ushort4*)lo)[i] = l;
}

// ---------------------------------------------------------------
// w[K][Nn] fp32 -> B-fragment-packed hi/lo bf16.
// chunk(nt,kt,lane) 16B: col c=nt*16+(lane&15), k=kt*32+(lane>>4)*8+j
// linear chunk index = (nt*KT + kt)*64 + lane
// ---------------------------------------------------------------
__global__ __launch_bounds__(256) void convT_pack(const float* __restrict__ in,
                                                  bf16x8* __restrict__ hi,
                                                  bf16x8* __restrict__ lo,
                                                  int K, int Nn) {
    int KT = K >> 5;
    int nt = blockIdx.x;
    int kt = blockIdx.y * 4 + (threadIdx.x >> 6);
    int lane = threadIdx.x & 63;
    int c = nt * 16 + (lane & 15);
    int kbase = kt * 32 + (lane >> 4) * 8;
    bf16x8 h, l;
    #pragma unroll
    for (int j = 0; j < 8; ++j) {
        float v = in[(size_t)(kbase + j) * Nn + c];
        unsigned short hv = f2bf(v);
        h[j] = (short)hv;
        l[j] = (short)f2bf(v - bf2f(hv));
    }
    int idx = (nt * KT + kt) * 64 + lane;
    hi[idx] = h;
    lo[idx] = l;
}

// ---------------------------------------------------------------
// split-bf16 MFMA GEMM, B direct-from-global (packed fragments).
// A hi/lo [M][K] bf16 via LDS; Bp hi/lo fragment-packed; C fp32.
// 128x128 tile, BK=32, 4 waves (2x2 of 64x64), 16x16x32 MFMA.
// ---------------------------------------------------------------
__global__ __launch_bounds__(256) void gemm_bdirect(const unsigned short* __restrict__ Ahi,
                                                    const unsigned short* __restrict__ Alo,
                                                    const bf16x8* __restrict__ Bph,
                                                    const bf16x8* __restrict__ Bpl,
                                                    float* __restrict__ Cout,
                                                    int K, int Nn) {
    __shared__ bf16x8 AhS[512], AlS[512];   // 2 x 8KB
    int tid = threadIdx.x;
    int wv = tid >> 6, lane = tid & 63;
    int m0 = blockIdx.x * 128, n0 = blockIdx.y * 128;   // m fastest: same-n blocks cluster per XCD
    int wm = (wv >> 1) * 64, wn = (wv & 1) * 64;
    int KT = K >> 5;

    f32x4 acc[4][4];
    #pragma unroll
    for (int a = 0; a < 4; ++a)
        #pragma unroll
        for (int b = 0; b < 4; ++b) acc[a][b] = (f32x4){0.f, 0.f, 0.f, 0.f};

    int fr = lane & 15, fkg = lane >> 4;
    int ntb = (n0 >> 4) + (wn >> 4);

    for (int kt = 0; kt < KT; ++kt) {
        int k0 = kt * 32;
        #pragma unroll
        for (int c2 = 0; c2 < 2; ++c2) {
            int chunk = wv * 2 + c2;          // 0..7
            int g = chunk * 64 + lane;        // 0..511
            int kg = g >> 7, row = g & 127;
            size_t ao = (size_t)(m0 + row) * K + k0 + kg * 8;
            gll16(Ahi + ao, &AhS[chunk * 64]);
            gll16(Alo + ao, &AlS[chunk * 64]);
        }
        bf16x8 bh[4], bl[4];
        #pragma unroll
        for (int ni = 0; ni < 4; ++ni) {
            int bidx = ((ntb + ni) * KT + kt) * 64 + lane;
            bh[ni] = Bph[bidx];
            bl[ni] = Bpl[bidx];
        }
        __syncthreads();
        bf16x8 ah[4], al[4];
        #pragma unroll
        for (int t = 0; t < 4; ++t) {
            ah[t] = AhS[fkg * 128 + wm + t * 16 + fr];
            al[t] = AlS[fkg * 128 + wm + t * 16 + fr];
        }
        #pragma unroll
        for (int mi = 0; mi < 4; ++mi)
            #pragma unroll
            for (int ni = 0; ni < 4; ++ni) {
                acc[mi][ni] = __builtin_amdgcn_mfma_f32_16x16x32_bf16(ah[mi], bh[ni], acc[mi][ni], 0, 0, 0);
                acc[mi][ni] = __builtin_amdgcn_mfma_f32_16x16x32_bf16(ah[mi], bl[ni], acc[mi][ni], 0, 0, 0);
                acc[mi][ni] = __builtin_amdgcn_mfma_f32_16x16x32_bf16(al[mi], bh[ni], acc[mi][ni], 0, 0, 0);
            }
        __syncthreads();
    }

    int cl = lane & 15, rq = (lane >> 4) * 4;
    #pragma unroll
    for (int ni = 0; ni < 4; ++ni) {
        int cc = n0 + wn + ni * 16 + cl;
        #pragma unroll
        for (int mi = 0; mi < 4; ++mi) {
            int rb = m0 + wm + mi * 16 + rq;
            #pragma unroll
            for (int r = 0; r < 4; ++r)
                Cout[(size_t)(rb + r) * Nn + cc] = acc[mi][ni][r];
        }
    }
}

// ---------------------------------------------------------------
// stats stage 1: per-(b,h), per-128-row-chunk partial sums of q,k,v.
// ---------------------------------------------------------------
__global__ __launch_bounds__(256) void stats_part(const float* __restrict__ qkv,
                                                  float* __restrict__ part) {
    int bh = blockIdx.x; int b = bh >> 3; int h = bh & 7;
    int chunk = blockIdx.y;
    int tid = threadIdx.x; int d = tid & 63; int g = tid >> 6;
    const float* base = qkv + (size_t)b * Nseq * QKVC + h * Dh + d;
    float sq = 0.f, sk = 0.f, svv = 0.f;
    int n0 = chunk * 128;
    for (int n = n0 + g; n < n0 + 128; n += 4) {
        const float* p = base + (size_t)n * QKVC;
        sq += p[0]; sk += p[512]; svv += p[1024];
    }
    __shared__ float red[3][4][64];
    red[0][g][d] = sq; red[1][g][d] = sk; red[2][g][d] = svv;
    __syncthreads();
    if (tid < 64) {
        size_t o = ((size_t)(bh * 16 + chunk) * 3) * 64 + d;
        part[o]       = red[0][0][d] + red[0][1][d] + red[0][2][d] + red[0][3][d];
        part[o + 64]  = red[1][0][d] + red[1][1][d] + red[1][2][d] + red[1][3][d];
        part[o + 128] = red[2][0][d] + red[2][1][d] + red[2][2][d] + red[2][3][d];
    }
}

__global__ __launch_bounds__(256) void stats_final(const float* __restrict__ part,
                                                   float* qmean, float* kmean, float* sv) {
    int bh = blockIdx.x;
    int tid = threadIdx.x;
    if (tid >= 192) return;
    int comp = tid >> 6, d = tid & 63;
    float s = 0.f;
    for (int c = 0; c < 16; ++c)
        s += part[((size_t)(bh * 16 + c) * 3 + comp) * 64 + d];
    if (comp == 0)      qmean[bh * 64 + d] = s * (1.0f / Nseq);
    else if (comp == 1) kmean[bh * 64 + d] = s * (1.0f / Nseq);
    else                sv[bh * 64 + d]    = s;
}

// ---------------------------------------------------------------
// row/col rank-1 scores (float4 loads)
// ---------------------------------------------------------------
__global__ __launch_bounds__(256) void score_kernel(const float* __restrict__ qkv,
                                                    const float* __restrict__ qmean,
                                                    const float* __restrict__ kmean,
                                                    float* rsc, float* csc) {
    int bh = blockIdx.x; int b = bh >> 3, h = bh & 7;
    int i = blockIdx.y * 256 + threadIdx.x;
    __shared__ float qm[64], km[64];
    if (threadIdx.x < 64) {
        qm[threadIdx.x] = qmean[bh * 64 + threadIdx.x];
        km[threadIdx.x] = kmean[bh * 64 + threadIdx.x];
    }
    __syncthreads();
    const float* rowp = qkv + (size_t)b * Nseq * QKVC + (size_t)i * QKVC + h * Dh;
    const float4* qp4 = (const float4*)rowp;
    const float4* kp4 = (const float4*)(rowp + 512);
    float r = 0.f, c = 0.f;
    #pragma unroll
    for (int d4 = 0; d4 < 16; ++d4) {
        float4 q = qp4[d4], k = kp4[d4];
        float4 m1 = *(const float4*)&km[d4 * 4];
        float4 m2 = *(const float4*)&qm[d4 * 4];
        r += q.x * m1.x + q.y * m1.y + q.z * m1.z + q.w * m1.w;
        c += k.x * m2.x + k.y * m2.y + k.z * m2.z + k.w * m2.w;
    }
    rsc[(size_t)bh * Nseq + i] = r * 0.125f;
    csc[(size_t)bh * Nseq + i] = c * 0.125f;
}

// ---------------------------------------------------------------
// top-256 by rank counting; also emits rankmap for ROW selection.
// ---------------------------------------------------------------
__global__ __launch_bounds__(256) void topk_kernel(const float* __restrict__ rsc,
                                                   const float* __restrict__ csc,
                                                   int* ridx, int* cidx, int* rankmap) {
    int selid = blockIdx.y;
    int bh = selid >> 1, which = selid & 1;
    const float* sin = which ? (csc + (size_t)bh * Nseq) : (rsc + (size_t)bh * Nseq);
    int* outp = which ? (cidx + bh * TK) : (ridx + bh * TK);
    __shared__ unsigned long long keys[Nseq];
    int tid = threadIdx.x;
    for (int i = tid; i < Nseq; i += 256) {
        unsigned u = __float_as_uint(sin[i]);
        u = (u & 0x80000000u) ? ~u : (u | 0x80000000u);
        keys[i] = ((unsigned long long)u << 32) | (unsigned)(Nseq - 1 - i);
    }
    __syncthreads();
    int i = blockIdx.x * 256 + tid;
    unsigned long long ki = keys[i];
    int rank = 0;
    #pragma unroll 8
    for (int j = 0; j < Nseq; ++j) rank += (keys[j] > ki) ? 1 : 0;
    if (rank < TK) outp[rank] = i;
    if (which == 0) rankmap[(size_t)bh * Nseq + i] = (rank < TK) ? rank : -1;
}

// ---------------------------------------------------------------
// Fused attention for selected rows: QK^T -> softmax -> PV.
// grid (BH, 8), 32 rows/block. Outputs compact delta[bh][256][64]
// where delta = attended_out - uniform_mean(v).
// LDS: Kt[64][256] (reused as E[32][256]) + Vt[64][260 pad] + Qs.
// ---------------------------------------------------------------
#define PADV 260
__global__ __launch_bounds__(256) void attn_fused(const float* __restrict__ qkv,
                                                  const int* __restrict__ ridx,
                                                  const int* __restrict__ cidx,
                                                  const float* __restrict__ sv,
                                                  float* __restrict__ delta) {
    int bh = blockIdx.x; int b = bh >> 3, h = bh & 7;
    int rblk = blockIdx.y;
    __shared__ float Kt[64 * 256];       // 64KB; later overwritten by E[32][256]
    __shared__ float Vt[64 * PADV];      // 65KB
    __shared__ float Qs[32 * 64];        // 8KB
    __shared__ float umS[32], izS[32];
    int tid = threadIdx.x;
    size_t base = (size_t)b * Nseq * QKVC;
    {
        int j = tid;
        int col = cidx[bh * TK + j];
        const float* kp = qkv + base + (size_t)col * QKVC + 512 + h * Dh;
        #pragma unroll 8
        for (int d = 0; d < 64; ++d) Kt[d * 256 + j] = kp[d];
        #pragma unroll 8
        for (int d = 0; d < 64; ++d) Vt[d * PADV + j] = kp[512 + d];
    }
    for (int idx = tid; idx < 32 * 64; idx += 256) {
        int il = idx >> 6, d = idx & 63;
        int row = ridx[bh * TK + rblk * 32 + il];
        Qs[idx] = qkv[base + (size_t)row * QKVC + h * Dh + d];
    }
    __syncthreads();

    int wave = tid >> 6, lane = tid & 63;
    int iw0 = wave * 8;
    // ---- E phase: lane owns columns j = 4*lane..4*lane+3
    float e[8][4];
    #pragma unroll
    for (int r = 0; r < 8; ++r)
        #pragma unroll
        for (int t = 0; t < 4; ++t) e[r][t] = 0.f;
    for (int d = 0; d < 64; ++d) {
        float4 kv = *(const float4*)&Kt[d * 256 + 4 * lane];
        #pragma unroll
        for (int r = 0; r < 8; ++r) {
            float qd = Qs[(iw0 + r) * 64 + d];
            e[r][0] += qd * kv.x; e[r][1] += qd * kv.y;
            e[r][2] += qd * kv.z; e[r][3] += qd * kv.w;
        }
    }
    #pragma unroll
    for (int r = 0; r < 8; ++r) {
        float s0 = e[r][0] * 0.125f, s1 = e[r][1] * 0.125f;
        float s2 = e[r][2] * 0.125f, s3 = e[r][3] * 0.125f;
        float mx = fmaxf(fmaxf(s0, s1), fmaxf(s2, s3));
        #pragma unroll
        for (int off = 32; off; off >>= 1) mx = fmaxf(mx, __shfl_xor(mx, off, 64));
        mx = fmaxf(mx, 0.0f);
        float e0 = __expf(s0 - mx), e1 = __expf(s1 - mx);
        float e2 = __expf(s2 - mx), e3 = __expf(s3 - mx);
        float zs = e0 + e1 + e2 + e3;
        #pragma unroll
        for (int off = 32; off; off >>= 1) zs += __shfl_xor(zs, off, 64);
        if (lane == 0) {
            float em = __expf(-mx);
            umS[iw0 + r] = em;
            izS[iw0 + r] = 1.0f / ((float)(Nseq - TK) * em + zs);
        }
        e[r][0] = e0; e[r][1] = e1; e[r][2] = e2; e[r][3] = e3;
    }
    __syncthreads();             // everyone done reading Kt
    float* E = Kt;
    #pragma unroll
    for (int r = 0; r < 8; ++r)
        *(float4*)&E[(iw0 + r) * 256 + 4 * lane] = (float4){e[r][0], e[r][1], e[r][2], e[r][3]};
    __syncthreads();
    // ---- PV phase: lane owns output dim d = lane
    float ssel = 0.f;
    for (int jc = 0; jc < 64; ++jc) {
        float4 vv = *(const float4*)&Vt[lane * PADV + 4 * jc];
        ssel += vv.x + vv.y + vv.z + vv.w;
    }
    float svd = sv[bh * 64 + lane];
    float sadj = svd - ssel;
    float uval = svd * (1.0f / Nseq);
    float acc[8];
    #pragma unroll
    for (int r = 0; r < 8; ++r) acc[r] = 0.f;
    for (int jc = 0; jc < 64; ++jc) {
        float4 vv = *(const float4*)&Vt[lane * PADV + 4 * jc];
        #pragma unroll
        for (int r = 0; r < 8; ++r) {
            float4 ev = *(const float4*)&E[(iw0 + r) * 256 + 4 * jc];
            acc[r] += ev.x * vv.x + ev.y * vv.y + ev.z * vv.z + ev.w * vv.w;
        }
    }
    #pragma unroll
    for (int r = 0; r < 8; ++r) {
        int i = rblk * 32 + iw0 + r;
        float outv = (umS[iw0 + r] * sadj + acc[r]) * izS[iw0 + r];
        delta[((size_t)bh * TK + i) * 64 + lane] = outv - uval;
    }
}

// ---------------------------------------------------------------
// ubase[b][c] = concat_h(sv/N) @ w_out + b_out.  grid (4, 8).
// ---------------------------------------------------------------
__global__ __launch_bounds__(256) void ubase_kernel(const float* __restrict__ sv,
                                                    const float* __restrict__ w_out,
                                                    const float* __restrict__ b_out,
                                                    float* __restrict__ ubase) {
    int b = blockIdx.x;
    int c0 = blockIdx.y * 64;
    int tid = threadIdx.x;
    int c = tid & 63, kg = tid >> 6;
    float s = 0.f;
    for (int k = kg * 128; k < kg * 128 + 128; ++k) {
        float hu = sv[(b * 8 + (k >> 6)) * 64 + (k & 63)] * (1.0f / Nseq);
        s += hu * w_out[(size_t)k * 512 + c0 + c];
    }
    __shared__ float red[4][64];
    red[kg][c] = s;
    __syncthreads();
    if (tid < 64)
        ubase[b * 512 + c0 + c] = red[0][c] + red[1][c] + red[2][c] + red[3][c] + b_out[c0 + c];
}

// ---------------------------------------------------------------
// deltaout[bh][256][512] = delta[bh][256][64] @ w_out[h*64:,:]
// fp32, grid (4 coltile, 2 rowhalf, 32 bh), 128x128 per block.
// ---------------------------------------------------------------
__global__ __launch_bounds__(256) void deltamm(const float* __restrict__ delta,
                                               const float* __restrict__ w_out,
                                               float* __restrict__ deltaout) {
    int ct = blockIdx.x, rh = blockIdx.y, bh = blockIdx.z;
    int h = bh & 7;
    __shared__ float As[128][65];
    __shared__ float Ws[64][132];
    int tid = threadIdx.x;
    for (int idx = tid; idx < 128 * 64; idx += 256) {
        int row = idx >> 6, k = idx & 63;
        As[row][k] = delta[((size_t)bh * TK + rh * 128 + row) * 64 + k];
    }
    for (int idx = tid; idx < 64 * 128; idx += 256) {
        int k = idx >> 7, c = idx & 127;
        Ws[k][c] = w_out[(size_t)(h * 64 + k) * 512 + ct * 128 + c];
    }
    __syncthreads();
    int tx = tid & 15, ty = tid >> 4;
    float acc[8][8];
    #pragma unroll
    for (int r = 0; r < 8; ++r)
        #pragma unroll
        for (int c = 0; c < 8; ++c) acc[r][c] = 0.f;
    for (int k = 0; k < 64; ++k) {
        float a[8], bv[8];
        #pragma unroll
        for (int r = 0; r < 8; ++r) a[r] = As[ty * 8 + r][k];
        #pragma unroll
        for (int cc = 0; cc < 4; ++cc) {
            bv[cc]     = Ws[k][tx * 4 + cc];
            bv[4 + cc] = Ws[k][64 + tx * 4 + cc];
        }
        #pragma unroll
        for (int r = 0; r < 8; ++r)
            #pragma unroll
            for (int c = 0; c < 8; ++c) acc[r][c] += a[r] * bv[c];
    }
    #pragma unroll
    for (int r = 0; r < 8; ++r) {
        size_t ro = ((size_t)bh * TK + rh * 128 + ty * 8 + r) * 512 + ct * 128;
        #pragma unroll
        for (int cc = 0; cc < 4; ++cc) {
            deltaout[ro + tx * 4 + cc]      = acc[r][cc];
            deltaout[ro + 64 + tx * 4 + cc] = acc[r][4 + cc];
        }
    }
}

// ---------------------------------------------------------------
// out[b][i][:] = ubase[b][:] + sum_h deltaout[bh][rankmap[bh][i]][:]
// ---------------------------------------------------------------
__global__ __launch_bounds__(256) void compose(const float* __restrict__ ubase,
                                               const int* __restrict__ rankmap,
                                               const float* __restrict__ deltaout,
                                               float* __restrict__ out) {
    int r0 = blockIdx.x * 4;
    int b = r0 >> 11;
    int tid = threadIdx.x;
    float u0 = ubase[b * 512 + tid];
    float u1 = ubase[b * 512 + 256 + tid];
    for (int rr = 0; rr < 4; ++rr) {
        int i = (r0 + rr) & 2047;
        float a0 = u0, a1 = u1;
        #pragma unroll
        for (int h = 0; h < 8; ++h) {
            int rk = rankmap[(size_t)(b * 8 + h) * Nseq + i];
            if (rk >= 0) {
                const float* dp = deltaout + ((size_t)(b * 8 + h) * TK + rk) * 512;
                a0 += dp[tid];
                a1 += dp[256 + tid];
            }
        }
        float* op = out + ((size_t)b * Nseq + i) * 512;
        op[tid] = a0;
        op[256 + tid] = a1;
    }
}

extern "C" void kernel_launch(void* const* d_in, const int* in_sizes, int n_in,
                              void* d_out, int out_size, void* d_ws, size_t ws_size,
                              hipStream_t stream) {
    const float* x     = (const float*)d_in[0];
    const float* w_qkv = (const float*)d_in[1];
    const float* w_out = (const float*)d_in[2];
    const float* b_out = (const float*)d_in[3];
    float* out = (float*)d_out;

    float* ws = (float*)d_ws;
    float* qkv = ws;                                                   // 12,582,912 f
    bf16x8* Bp_hi = (bf16x8*)(qkv + (size_t)Bsz * Nseq * QKVC);        // 393,216 f each
    bf16x8* Bp_lo = (bf16x8*)((float*)Bp_hi + 393216);
    float* qmean = (float*)Bp_lo + 393216;
    float* kmean = qmean + BH * Dh;
    float* sv    = kmean + BH * Dh;
    float* rsc   = sv + BH * Dh;                                       // 65,536 f
    float* csc   = rsc + (size_t)BH * Nseq;
    int*   ridx  = (int*)(csc + (size_t)BH * Nseq);
    int*   cidx  = ridx + BH * TK;
    int*   rankmap = cidx + BH * TK;                                   // 65,536 i
    float* ubase = (float*)(rankmap + (size_t)BH * Nseq);              // 2,048 f
    float* delta = ubase + Bsz * Cdim;                                 // 524,288 f
    float* deltaout = delta + (size_t)BH * TK * 64;                    // 4,194,304 f
    // xhi/xlo alias deltaout (dead until deltamm, which runs after gemm1)
    unsigned short* xhi = (unsigned short*)deltaout;                   // 4,194,304 ush
    unsigned short* xlo = xhi + (size_t)MROWS * Cdim;
    float* part = rsc;   // stats partials alias rsc (dead until score)

    // 0. splits / packing
    conv_hl<<<(MROWS * Cdim / 4 + 255) / 256, 256, 0, stream>>>(x, xhi, xlo, MROWS * Cdim / 4);
    convT_pack<<<dim3(QKVC / 16, 4), 256, 0, stream>>>(w_qkv, Bp_hi, Bp_lo, Cdim, QKVC);
    // 1. qkv = x @ w_qkv (split-bf16 MFMA, B direct from L2)
    gemm_bdirect<<<dim3(MROWS / 128, QKVC / 128), 256, 0, stream>>>(xhi, xlo, Bp_hi, Bp_lo,
                                                                    qkv, Cdim, QKVC);
    // 2. stats
    stats_part<<<dim3(BH, 16), 256, 0, stream>>>(qkv, part);
    stats_final<<<BH, 256, 0, stream>>>(part, qmean, kmean, sv);
    // 3. rank-1 scores
    score_kernel<<<dim3(BH, Nseq / 256), 256, 0, stream>>>(qkv, qmean, kmean, rsc, csc);
    // 4. top-256 + rankmap
    topk_kernel<<<dim3(Nseq / 256, BH * 2), 256, 0, stream>>>(rsc, csc, ridx, cidx, rankmap);
    // 5. fused attention -> compact delta
    attn_fused<<<dim3(BH, 8), 256, 0, stream>>>(qkv, ridx, cidx, sv, delta);
    // 6. uniform base rows
    ubase_kernel<<<dim3(Bsz, 8), 256, 0, stream>>>(sv, w_out, b_out, ubase);
    // 7. delta @ w_out (compact fp32 GEMM)
    deltamm<<<dim3(4, 2, BH), 256, 0, stream>>>(delta, w_out, deltaout);
    // 8. compose final output
    compose<<<MROWS / 4, 256, 0, stream>>>(ubase, rankmap, deltaout, out);
}

// Round 5
// 223.236 us; speedup vs baseline: 2.8588x; 1.1244x over previous
//
#include <hip/hip_runtime.h>
#include <math.h>

#define Bsz 4
#define Nseq 2048
#define Cdim 512
#define Hn 8
#define Dh 64
#define TK 256
#define BH (Bsz*Hn)          // 32
#define MROWS (Bsz*Nseq)     // 8192
#define QKVC 1536

typedef __attribute__((ext_vector_type(8))) short bf16x8;
typedef __attribute__((ext_vector_type(4))) float f32x4;

__device__ __forceinline__ unsigned short f2bf(float x) {
    unsigned u = __float_as_uint(x);
    unsigned r = (u + 0x7fffu + ((u >> 16) & 1u)) >> 16;   // round-to-nearest-even
    return (unsigned short)r;
}
__device__ __forceinline__ float bf2f(unsigned short h) {
    return __uint_as_float((unsigned)h << 16);
}

// ---------------------------------------------------------------
// x[M][K] fp32 -> A-fragment-packed hi/lo bf16.
// chunk(t16, kt, lane): row m = t16*16+(lane&15), k = kt*32+(lane>>4)*8+j
// linear chunk idx = (t16*KT + kt)*64 + lane, KT = K/32 = 16.
// ---------------------------------------------------------------
__global__ __launch_bounds__(256) void conv_apack(const float* __restrict__ x,
                                                  bf16x8* __restrict__ hi,
                                                  bf16x8* __restrict__ lo) {
    int cid = blockIdx.x * 256 + threadIdx.x;
    int lane = cid & 63;
    int rest = cid >> 6;
    int kt = rest & 15;          // KT = 16
    int t16 = rest >> 4;
    int m = t16 * 16 + (lane & 15);
    int k0 = kt * 32 + (lane >> 4) * 8;
    const float* p = x + (size_t)m * Cdim + k0;
    float4 v0 = *(const float4*)p;
    float4 v1 = *(const float4*)(p + 4);
    float vv[8] = {v0.x, v0.y, v0.z, v0.w, v1.x, v1.y, v1.z, v1.w};
    bf16x8 h, l;
    #pragma unroll
    for (int j = 0; j < 8; ++j) {
        unsigned short hv = f2bf(vv[j]);
        h[j] = (short)hv;
        l[j] = (short)f2bf(vv[j] - bf2f(hv));
    }
    hi[cid] = h;
    lo[cid] = l;
}

// ---------------------------------------------------------------
// w[K][Nn] fp32 -> B-fragment-packed hi/lo bf16 (as round 4).
// ---------------------------------------------------------------
__global__ __launch_bounds__(256) void convT_pack(const float* __restrict__ in,
                                                  bf16x8* __restrict__ hi,
                                                  bf16x8* __restrict__ lo,
                                                  int K, int Nn) {
    int KT = K >> 5;
    int nt = blockIdx.x;
    int kt = blockIdx.y * 4 + (threadIdx.x >> 6);
    int lane = threadIdx.x & 63;
    int c = nt * 16 + (lane & 15);
    int kbase = kt * 32 + (lane >> 4) * 8;
    bf16x8 h, l;
    #pragma unroll
    for (int j = 0; j < 8; ++j) {
        float v = in[(size_t)(kbase + j) * Nn + c];
        unsigned short hv = f2bf(v);
        h[j] = (short)hv;
        l[j] = (short)f2bf(v - bf2f(hv));
    }
    int idx = (nt * KT + kt) * 64 + lane;
    hi[idx] = h;
    lo[idx] = l;
}

#define MFMA3(AH, AL, BHH, BLL)                                                          \
    _Pragma("unroll")                                                                    \
    for (int mi = 0; mi < 4; ++mi)                                                       \
        _Pragma("unroll")                                                                \
        for (int ni = 0; ni < 4; ++ni) {                                                 \
            acc[mi][ni] = __builtin_amdgcn_mfma_f32_16x16x32_bf16(AH[mi], BHH[ni], acc[mi][ni], 0, 0, 0); \
            acc[mi][ni] = __builtin_amdgcn_mfma_f32_16x16x32_bf16(AH[mi], BLL[ni], acc[mi][ni], 0, 0, 0); \
            acc[mi][ni] = __builtin_amdgcn_mfma_f32_16x16x32_bf16(AL[mi], BHH[ni], acc[mi][ni], 0, 0, 0); \
        }

// ---------------------------------------------------------------
// Barrier-free split-bf16 MFMA GEMM, both operands fragment-packed,
// loaded global->VGPR (no LDS staging, no K-loop barriers).
// Grid: 768 linear; XCD-aware decode: same-A-panel blocks share XCD.
// Epilogue: C write + deterministic per-mtile column sums (colpart).
// ---------------------------------------------------------------
__global__ __launch_bounds__(256, 2) void gemm_reg(const bf16x8* __restrict__ Aph,
                                                   const bf16x8* __restrict__ Apl,
                                                   const bf16x8* __restrict__ Bph,
                                                   const bf16x8* __restrict__ Bpl,
                                                   float* __restrict__ Cout,
                                                   float* __restrict__ colpart,
                                                   int K, int Nn) {
    int KT = K >> 5;                          // 16
    int NTI = Nn >> 7;                        // n-tiles of 128 (12)
    int bid = blockIdx.x;
    int xcd = bid & 7;
    int jj = bid >> 3;                        // 0..95
    int mtile = (jj / NTI) * 8 + xcd;         // 0..63 (A panel stays on one XCD)
    int nt = jj % NTI;
    int m0 = mtile * 128, n0 = nt * 128;
    int tid = threadIdx.x;
    int wv = tid >> 6, lane = tid & 63;
    int wm = (wv >> 1) * 64, wn = (wv & 1) * 64;

    f32x4 acc[4][4];
    #pragma unroll
    for (int a = 0; a < 4; ++a)
        #pragma unroll
        for (int b = 0; b < 4; ++b) acc[a][b] = (f32x4){0.f, 0.f, 0.f, 0.f};

    int mt16 = (m0 + wm) >> 4;
    int nt16 = (n0 + wn) >> 4;
    const bf16x8* A_h = Aph + (size_t)mt16 * KT * 64 + lane;
    const bf16x8* A_l = Apl + (size_t)mt16 * KT * 64 + lane;
    const bf16x8* B_h = Bph + (size_t)nt16 * KT * 64 + lane;
    const bf16x8* B_l = Bpl + (size_t)nt16 * KT * 64 + lane;
    int sT = KT * 64;                          // chunk stride per 16-tile

    bf16x8 cah[4], cal[4], cbh[4], cbl[4];
    bf16x8 nah[4], nal[4], nbh[4], nbl[4];
    #pragma unroll
    for (int t = 0; t < 4; ++t) {
        cah[t] = A_h[t * sT]; cal[t] = A_l[t * sT];
        cbh[t] = B_h[t * sT]; cbl[t] = B_l[t * sT];
    }
    for (int kt = 0; kt < KT; kt += 2) {
        int o1 = (kt + 1) * 64;
        #pragma unroll
        for (int t = 0; t < 4; ++t) {
            nah[t] = A_h[t * sT + o1]; nal[t] = A_l[t * sT + o1];
            nbh[t] = B_h[t * sT + o1]; nbl[t] = B_l[t * sT + o1];
        }
        MFMA3(cah, cal, cbh, cbl)
        if (kt + 2 < KT) {
            int o2 = (kt + 2) * 64;
            #pragma unroll
            for (int t = 0; t < 4; ++t) {
                cah[t] = A_h[t * sT + o2]; cal[t] = A_l[t * sT + o2];
                cbh[t] = B_h[t * sT + o2]; cbl[t] = B_l[t * sT + o2];
            }
        }
        MFMA3(nah, nal, nbh, nbl)
    }

    // C write: C/D layout col=lane&15, row=(lane>>4)*4+reg
    int cl = lane & 15, rq = (lane >> 4) * 4;
    #pragma unroll
    for (int ni = 0; ni < 4; ++ni) {
        int cc = n0 + wn + ni * 16 + cl;
        #pragma unroll
        for (int mi = 0; mi < 4; ++mi) {
            int rb = m0 + wm + mi * 16 + rq;
            #pragma unroll
            for (int r = 0; r < 4; ++r)
                Cout[(size_t)(rb + r) * Nn + cc] = acc[mi][ni][r];
        }
    }

    // deterministic column sums over this block's 128 rows
    __shared__ float cs[128];
    float s[4];
    #pragma unroll
    for (int ni = 0; ni < 4; ++ni) {
        float t = 0.f;
        #pragma unroll
        for (int mi = 0; mi < 4; ++mi)
            #pragma unroll
            for (int r = 0; r < 4; ++r) t += acc[mi][ni][r];
        t += __shfl_xor(t, 16, 64);
        t += __shfl_xor(t, 32, 64);
        s[ni] = t;
    }
    if (wm == 0 && lane < 16) {
        #pragma unroll
        for (int ni = 0; ni < 4; ++ni) cs[wn + ni * 16 + lane] = s[ni];
    }
    __syncthreads();
    if (wm == 64 && lane < 16) {
        #pragma unroll
        for (int ni = 0; ni < 4; ++ni) cs[wn + ni * 16 + lane] += s[ni];
    }
    __syncthreads();
    if (tid < 128) colpart[(size_t)mtile * Nn + n0 + tid] = cs[tid];
}

// ---------------------------------------------------------------
// stats from colpart: per-batch sums of q,k,v columns. grid (6, 4).
// ---------------------------------------------------------------
__global__ __launch_bounds__(256) void stats_final2(const float* __restrict__ colpart,
                                                    float* qmean, float* kmean, float* sv) {
    int b = blockIdx.y;
    int c = blockIdx.x * 256 + threadIdx.x;   // 0..1535
    float s = 0.f;
    #pragma unroll 4
    for (int mt = b * 16; mt < b * 16 + 16; ++mt)
        s += colpart[(size_t)mt * QKVC + c];
    int h = (c >> 6) & 7, d = c & 63;
    int bh = b * 8 + h;
    if (c < 512)       qmean[bh * 64 + d] = s * (1.0f / Nseq);
    else if (c < 1024) kmean[bh * 64 + d] = s * (1.0f / Nseq);
    else               sv[bh * 64 + d]    = s;
}

// ---------------------------------------------------------------
// row/col rank-1 scores (float4 loads)
// ---------------------------------------------------------------
__global__ __launch_bounds__(256) void score_kernel(const float* __restrict__ qkv,
                                                    const float* __restrict__ qmean,
                                                    const float* __restrict__ kmean,
                                                    float* rsc, float* csc) {
    int bh = blockIdx.x; int b = bh >> 3, h = bh & 7;
    int i = blockIdx.y * 256 + threadIdx.x;
    __shared__ float qm[64], km[64];
    if (threadIdx.x < 64) {
        qm[threadIdx.x] = qmean[bh * 64 + threadIdx.x];
        km[threadIdx.x] = kmean[bh * 64 + threadIdx.x];
    }
    __syncthreads();
    const float* rowp = qkv + (size_t)b * Nseq * QKVC + (size_t)i * QKVC + h * Dh;
    const float4* qp4 = (const float4*)rowp;
    const float4* kp4 = (const float4*)(rowp + 512);
    float r = 0.f, c = 0.f;
    #pragma unroll
    for (int d4 = 0; d4 < 16; ++d4) {
        float4 q = qp4[d4], k = kp4[d4];
        float4 m1 = *(const float4*)&km[d4 * 4];
        float4 m2 = *(const float4*)&qm[d4 * 4];
        r += q.x * m1.x + q.y * m1.y + q.z * m1.z + q.w * m1.w;
        c += k.x * m2.x + k.y * m2.y + k.z * m2.z + k.w * m2.w;
    }
    rsc[(size_t)bh * Nseq + i] = r * 0.125f;
    csc[(size_t)bh * Nseq + i] = c * 0.125f;
}

// ---------------------------------------------------------------
// top-256 by rank counting; also emits rankmap for ROW selection.
// ---------------------------------------------------------------
__global__ __launch_bounds__(256) void topk_kernel(const float* __restrict__ rsc,
                                                   const float* __restrict__ csc,
                                                   int* ridx, int* cidx, int* rankmap) {
    int selid = blockIdx.y;
    int bh = selid >> 1, which = selid & 1;
    const float* sin = which ? (csc + (size_t)bh * Nseq) : (rsc + (size_t)bh * Nseq);
    int* outp = which ? (cidx + bh * TK) : (ridx + bh * TK);
    __shared__ unsigned long long keys[Nseq];
    int tid = threadIdx.x;
    for (int i = tid; i < Nseq; i += 256) {
        unsigned u = __float_as_uint(sin[i]);
        u = (u & 0x80000000u) ? ~u : (u | 0x80000000u);
        keys[i] = ((unsigned long long)u << 32) | (unsigned)(Nseq - 1 - i);
    }
    __syncthreads();
    int i = blockIdx.x * 256 + tid;
    unsigned long long ki = keys[i];
    int rank = 0;
    #pragma unroll 8
    for (int j = 0; j < Nseq; ++j) rank += (keys[j] > ki) ? 1 : 0;
    if (rank < TK) outp[rank] = i;
    if (which == 0) rankmap[(size_t)bh * Nseq + i] = (rank < TK) ? rank : -1;
}

// ---------------------------------------------------------------
// Fused attention for selected rows -> compact delta[bh][256][64].
// ---------------------------------------------------------------
#define PADV 260
__global__ __launch_bounds__(256) void attn_fused(const float* __restrict__ qkv,
                                                  const int* __restrict__ ridx,
                                                  const int* __restrict__ cidx,
                                                  const float* __restrict__ sv,
                                                  float* __restrict__ delta) {
    int bh = blockIdx.x; int b = bh >> 3, h = bh & 7;
    int rblk = blockIdx.y;
    __shared__ float Kt[64 * 256];       // 64KB; later overwritten by E[32][256]
    __shared__ float Vt[64 * PADV];      // 65KB
    __shared__ float Qs[32 * 64];        // 8KB
    __shared__ float umS[32], izS[32];
    int tid = threadIdx.x;
    size_t base = (size_t)b * Nseq * QKVC;
    {
        int j = tid;
        int col = cidx[bh * TK + j];
        const float* kp = qkv + base + (size_t)col * QKVC + 512 + h * Dh;
        #pragma unroll 8
        for (int d = 0; d < 64; ++d) Kt[d * 256 + j] = kp[d];
        #pragma unroll 8
        for (int d = 0; d < 64; ++d) Vt[d * PADV + j] = kp[512 + d];
    }
    for (int idx = tid; idx < 32 * 64; idx += 256) {
        int il = idx >> 6, d = idx & 63;
        int row = ridx[bh * TK + rblk * 32 + il];
        Qs[idx] = qkv[base + (size_t)row * QKVC + h * Dh + d];
    }
    __syncthreads();

    int wave = tid >> 6, lane = tid & 63;
    int iw0 = wave * 8;
    float e[8][4];
    #pragma unroll
    for (int r = 0; r < 8; ++r)
        #pragma unroll
        for (int t = 0; t < 4; ++t) e[r][t] = 0.f;
    for (int d = 0; d < 64; ++d) {
        float4 kv = *(const float4*)&Kt[d * 256 + 4 * lane];
        #pragma unroll
        for (int r = 0; r < 8; ++r) {
            float qd = Qs[(iw0 + r) * 64 + d];
            e[r][0] += qd * kv.x; e[r][1] += qd * kv.y;
            e[r][2] += qd * kv.z; e[r][3] += qd * kv.w;
        }
    }
    #pragma unroll
    for (int r = 0; r < 8; ++r) {
        float s0 = e[r][0] * 0.125f, s1 = e[r][1] * 0.125f;
        float s2 = e[r][2] * 0.125f, s3 = e[r][3] * 0.125f;
        float mx = fmaxf(fmaxf(s0, s1), fmaxf(s2, s3));
        #pragma unroll
        for (int off = 32; off; off >>= 1) mx = fmaxf(mx, __shfl_xor(mx, off, 64));
        mx = fmaxf(mx, 0.0f);
        float e0 = __expf(s0 - mx), e1 = __expf(s1 - mx);
        float e2 = __expf(s2 - mx), e3 = __expf(s3 - mx);
        float zs = e0 + e1 + e2 + e3;
        #pragma unroll
        for (int off = 32; off; off >>= 1) zs += __shfl_xor(zs, off, 64);
        if (lane == 0) {
            float em = __expf(-mx);
            umS[iw0 + r] = em;
            izS[iw0 + r] = 1.0f / ((float)(Nseq - TK) * em + zs);
        }
        e[r][0] = e0; e[r][1] = e1; e[r][2] = e2; e[r][3] = e3;
    }
    __syncthreads();
    float* E = Kt;
    #pragma unroll
    for (int r = 0; r < 8; ++r)
        *(float4*)&E[(iw0 + r) * 256 + 4 * lane] = (float4){e[r][0], e[r][1], e[r][2], e[r][3]};
    __syncthreads();
    float ssel = 0.f;
    for (int jc = 0; jc < 64; ++jc) {
        float4 vv = *(const float4*)&Vt[lane * PADV + 4 * jc];
        ssel += vv.x + vv.y + vv.z + vv.w;
    }
    float svd = sv[bh * 64 + lane];
    float sadj = svd - ssel;
    float uval = svd * (1.0f / Nseq);
    float acc[8];
    #pragma unroll
    for (int r = 0; r < 8; ++r) acc[r] = 0.f;
    for (int jc = 0; jc < 64; ++jc) {
        float4 vv = *(const float4*)&Vt[lane * PADV + 4 * jc];
        #pragma unroll
        for (int r = 0; r < 8; ++r) {
            float4 ev = *(const float4*)&E[(iw0 + r) * 256 + 4 * jc];
            acc[r] += ev.x * vv.x + ev.y * vv.y + ev.z * vv.z + ev.w * vv.w;
        }
    }
    #pragma unroll
    for (int r = 0; r < 8; ++r) {
        int i = rblk * 32 + iw0 + r;
        float outv = (umS[iw0 + r] * sadj + acc[r]) * izS[iw0 + r];
        delta[((size_t)bh * TK + i) * 64 + lane] = outv - uval;
    }
}

// ---------------------------------------------------------------
// ubase[b][c] = concat_h(sv/N) @ w_out + b_out.  grid (4, 8).
// ---------------------------------------------------------------
__global__ __launch_bounds__(256) void ubase_kernel(const float* __restrict__ sv,
                                                    const float* __restrict__ w_out,
                                                    const float* __restrict__ b_out,
                                                    float* __restrict__ ubase) {
    int b = blockIdx.x;
    int c0 = blockIdx.y * 64;
    int tid = threadIdx.x;
    int c = tid & 63, kg = tid >> 6;
    float s = 0.f;
    for (int k = kg * 128; k < kg * 128 + 128; ++k) {
        float hu = sv[(b * 8 + (k >> 6)) * 64 + (k & 63)] * (1.0f / Nseq);
        s += hu * w_out[(size_t)k * 512 + c0 + c];
    }
    __shared__ float red[4][64];
    red[kg][c] = s;
    __syncthreads();
    if (tid < 64)
        ubase[b * 512 + c0 + c] = red[0][c] + red[1][c] + red[2][c] + red[3][c] + b_out[c0 + c];
}

// ---------------------------------------------------------------
// deltaout[bh][256][512] = delta[bh][256][64] @ w_out[h*64:,:]
// ---------------------------------------------------------------
__global__ __launch_bounds__(256) void deltamm(const float* __restrict__ delta,
                                               const float* __restrict__ w_out,
                                               float* __restrict__ deltaout) {
    int ct = blockIdx.x, rh = blockIdx.y, bh = blockIdx.z;
    int h = bh & 7;
    __shared__ float As[128][65];
    __shared__ float Ws[64][132];
    int tid = threadIdx.x;
    for (int idx = tid; idx < 128 * 64; idx += 256) {
        int row = idx >> 6, k = idx & 63;
        As[row][k] = delta[((size_t)bh * TK + rh * 128 + row) * 64 + k];
    }
    for (int idx = tid; idx < 64 * 128; idx += 256) {
        int k = idx >> 7, c = idx & 127;
        Ws[k][c] = w_out[(size_t)(h * 64 + k) * 512 + ct * 128 + c];
    }
    __syncthreads();
    int tx = tid & 15, ty = tid >> 4;
    float acc[8][8];
    #pragma unroll
    for (int r = 0; r < 8; ++r)
        #pragma unroll
        for (int c = 0; c < 8; ++c) acc[r][c] = 0.f;
    for (int k = 0; k < 64; ++k) {
        float a[8], bv[8];
        #pragma unroll
        for (int r = 0; r < 8; ++r) a[r] = As[ty * 8 + r][k];
        #pragma unroll
        for (int cc = 0; cc < 4; ++cc) {
            bv[cc]     = Ws[k][tx * 4 + cc];
            bv[4 + cc] = Ws[k][64 + tx * 4 + cc];
        }
        #pragma unroll
        for (int r = 0; r < 8; ++r)
            #pragma unroll
            for (int c = 0; c < 8; ++c) acc[r][c] += a[r] * bv[c];
    }
    #pragma unroll
    for (int r = 0; r < 8; ++r) {
        size_t ro = ((size_t)bh * TK + rh * 128 + ty * 8 + r) * 512 + ct * 128;
        #pragma unroll
        for (int cc = 0; cc < 4; ++cc) {
            deltaout[ro + tx * 4 + cc]      = acc[r][cc];
            deltaout[ro + 64 + tx * 4 + cc] = acc[r][4 + cc];
        }
    }
}

// ---------------------------------------------------------------
// out[b][i][:] = ubase[b][:] + sum_h deltaout[bh][rankmap[bh][i]][:]
// ---------------------------------------------------------------
__global__ __launch_bounds__(256) void compose(const float* __restrict__ ubase,
                                               const int* __restrict__ rankmap,
                                               const float* __restrict__ deltaout,
                                               float* __restrict__ out) {
    int r0 = blockIdx.x * 4;
    int b = r0 >> 11;
    int tid = threadIdx.x;
    float u0 = ubase[b * 512 + tid];
    float u1 = ubase[b * 512 + 256 + tid];
    for (int rr = 0; rr < 4; ++rr) {
        int i = (r0 + rr) & 2047;
        float a0 = u0, a1 = u1;
        #pragma unroll
        for (int h = 0; h < 8; ++h) {
            int rk = rankmap[(size_t)(b * 8 + h) * Nseq + i];
            if (rk >= 0) {
                const float* dp = deltaout + ((size_t)(b * 8 + h) * TK + rk) * 512;
                a0 += dp[tid];
                a1 += dp[256 + tid];
            }
        }
        float* op = out + ((size_t)b * Nseq + i) * 512;
        op[tid] = a0;
        op[256 + tid] = a1;
    }
}

extern "C" void kernel_launch(void* const* d_in, const int* in_sizes, int n_in,
                              void* d_out, int out_size, void* d_ws, size_t ws_size,
                              hipStream_t stream) {
    const float* x     = (const float*)d_in[0];
    const float* w_qkv = (const float*)d_in[1];
    const float* w_out = (const float*)d_in[2];
    const float* b_out = (const float*)d_in[3];
    float* out = (float*)d_out;

    float* ws = (float*)d_ws;
    float* qkv = ws;                                                   // 12,582,912 f
    bf16x8* Bp_hi = (bf16x8*)(qkv + (size_t)Bsz * Nseq * QKVC);        // 393,216 f
    bf16x8* Bp_lo = (bf16x8*)((float*)Bp_hi + 393216);                 // 393,216 f
    float* colpart = (float*)Bp_lo + 393216;                           // 98,304 f
    float* qmean = colpart + 64 * QKVC;
    float* kmean = qmean + BH * Dh;
    float* sv    = kmean + BH * Dh;
    float* rsc   = sv + BH * Dh;                                       // 65,536 f
    float* csc   = rsc + (size_t)BH * Nseq;
    int*   ridx  = (int*)(csc + (size_t)BH * Nseq);
    int*   cidx  = ridx + BH * TK;
    int*   rankmap = cidx + BH * TK;                                   // 65,536 i
    float* ubase = (float*)(rankmap + (size_t)BH * Nseq);              // 2,048 f
    float* delta = ubase + Bsz * Cdim;                                 // 524,288 f
    float* deltaout = delta + (size_t)BH * TK * 64;                    // 4,194,304 f
    // Ap_hi/Ap_lo alias deltaout (A frags dead after gemm1; deltaout written later)
    bf16x8* Ap_hi = (bf16x8*)deltaout;                                 // 2,097,152 f
    bf16x8* Ap_lo = (bf16x8*)(deltaout + 2097152);                     // 2,097,152 f

    // 0. fragment packing
    conv_apack<<<(MROWS / 16) * 16 * 64 / 256, 256, 0, stream>>>(x, Ap_hi, Ap_lo);
    convT_pack<<<dim3(QKVC / 16, 4), 256, 0, stream>>>(w_qkv, Bp_hi, Bp_lo, Cdim, QKVC);
    // 1. qkv = x @ w_qkv (barrier-free register-direct split-bf16 MFMA)
    //    + fused per-mtile column sums
    gemm_reg<<<(MROWS / 128) * (QKVC / 128), 256, 0, stream>>>(Ap_hi, Ap_lo, Bp_hi, Bp_lo,
                                                               qkv, colpart, Cdim, QKVC);
    // 2. stats from colpart
    stats_final2<<<dim3(QKVC / 256, Bsz), 256, 0, stream>>>(colpart, qmean, kmean, sv);
    // 3. rank-1 scores
    score_kernel<<<dim3(BH, Nseq / 256), 256, 0, stream>>>(qkv, qmean, kmean, rsc, csc);
    // 4. top-256 + rankmap
    topk_kernel<<<dim3(Nseq / 256, BH * 2), 256, 0, stream>>>(rsc, csc, ridx, cidx, rankmap);
    // 5. fused attention -> compact delta
    attn_fused<<<dim3(BH, 8), 256, 0, stream>>>(qkv, ridx, cidx, sv, delta);
    // 6. uniform base rows
    ubase_kernel<<<dim3(Bsz, 8), 256, 0, stream>>>(sv, w_out, b_out, ubase);
    // 7. delta @ w_out (compact fp32 GEMM)
    deltamm<<<dim3(4, 2, BH), 256, 0, stream>>>(delta, w_out, deltaout);
    // 8. compose final output
    compose<<<MROWS / 4, 256, 0, stream>>>(ubase, rankmap, deltaout, out);
}